// Round 11
// baseline (99.824 us; speedup 1.0000x reference)
//
#include <hip/hip_runtime.h>

#define B 8
#define N 1024
#define D_IN 64
#define H 128
#define HEADS 4
#define HD 32
#define L 2
#define EPS 1e-5f
#define NEG_BIG -1e30f
// 1/sqrt(32) * log2(e): softmax computed in base-2 domain (exp2f)
#define QSCALE (0.17677669529663687f * 1.4426950408889634f)

typedef __attribute__((ext_vector_type(8))) short bf16x8;
typedef __attribute__((ext_vector_type(4))) float f32x4;

__device__ __forceinline__ unsigned short f2bf(float f) {
    unsigned u = __float_as_uint(f);
    u = u + 0x7fffu + ((u >> 16) & 1u);
    return (unsigned short)(u >> 16);
}
__device__ __forceinline__ float bf2f(unsigned short s) {
    return __uint_as_float(((unsigned)s) << 16);
}
__device__ __forceinline__ void gload_lds16(const void* g, void* l) {
    __builtin_amdgcn_global_load_lds(
        (const __attribute__((address_space(1))) unsigned int*)g,
        (__attribute__((address_space(3))) unsigned int*)l,
        16, 0, 0);
}

#define NPACK 1024           // B*N*N/32/256
#define NPREP 579            // (L*3*H*H + L*3*H + L*H*H + H*H)/256
#define NENC  256            // B*N/32

// ======== fused front: adj-pack | weight-prep | encoder (independent roles) ========
__global__ __launch_bounds__(256) void front_kernel(
    const float* __restrict__ adj, const float* __restrict__ x,
    const float* __restrict__ enc_w, const float* __restrict__ eb,
    const float* __restrict__ q_w, const float* __restrict__ k_w,
    const float* __restrict__ v_w, const float* __restrict__ q_b,
    const float* __restrict__ k_b, const float* __restrict__ v_b,
    const float* __restrict__ o_w, const float* __restrict__ out_w,
    unsigned* __restrict__ mb, unsigned short* __restrict__ wqkv,
    float* __restrict__ bqkv, unsigned short* __restrict__ woh,
    unsigned short* __restrict__ wol, unsigned short* __restrict__ wfh,
    unsigned short* __restrict__ wfl, float* __restrict__ h,
    unsigned short* __restrict__ h_bf) {
    __shared__ unsigned short wt[H * D_IN];    // 16 KB (enc role only)
    __shared__ unsigned short at[32 * D_IN];   // 4 KB
    const int blk = blockIdx.x;
    const int t = threadIdx.x;

    if (blk < NPACK) {                 // ---- adj -> bitmask ----
        int wd = blk * 256 + t;
        const float4* src = (const float4*)(adj + (size_t)wd * 32);
        unsigned m = 0;
        #pragma unroll
        for (int c = 0; c < 8; ++c) {
            float4 f = src[c];
            if (f.x != 0.0f) m |= 1u << (c * 4 + 0);
            if (f.y != 0.0f) m |= 1u << (c * 4 + 1);
            if (f.z != 0.0f) m |= 1u << (c * 4 + 2);
            if (f.w != 0.0f) m |= 1u << (c * 4 + 3);
        }
        mb[wd] = m;
        return;
    }
    if (blk < NPACK + NPREP) {         // ---- weight prep ----
        int id = (blk - NPACK) * 256 + t;
        const int WQ = L * 3 * H * H;
        const int BQ = L * 3 * H;
        const int WO = L * H * H;
        if (id < WQ) {
            int layer = id / (3 * H * H);
            int r = id % (3 * H * H);
            int mat = r / (H * H);
            int e = r % (H * H);
            const float* src = mat == 0 ? q_w : (mat == 1 ? k_w : v_w);
            float f = src[layer * H * H + e];
            if (mat == 0) f *= QSCALE;
            wqkv[id] = f2bf(f);
            return;
        }
        id -= WQ;
        if (id < BQ) {
            int layer = id / (3 * H);
            int r = id % (3 * H);
            int mat = r / H;
            int e = r % H;
            const float* src = mat == 0 ? q_b : (mat == 1 ? k_b : v_b);
            float f = src[layer * H + e];
            if (mat == 0) f *= QSCALE;
            bqkv[id] = f;
            return;
        }
        id -= BQ;
        if (id < WO) {
            float f = o_w[id];
            unsigned short hi = f2bf(f);
            woh[id] = hi;
            wol[id] = f2bf(f - bf2f(hi));
            return;
        }
        id -= WO;
        {
            float f = out_w[id];
            unsigned short hi = f2bf(f);
            wfh[id] = hi;
            wfl[id] = f2bf(f - bf2f(hi));
        }
        return;
    }
    // ---- encoder: h = relu(x @ enc_w.T + b), 32-row blocks, in-kernel bf16 convert ----
    const int r0 = (blk - NPACK - NPREP) * 32;
    const int w = t >> 6, lane = t & 63, g = lane >> 4, c16 = lane & 15;
    const int rw = w & 1, chw = w >> 1;

    // stage enc_w (128x64) fp32 -> bf16 LDS, chunk-swizzled (key row&7)
    #pragma unroll
    for (int i = 0; i < 8; ++i) {
        int idx4 = i * 256 + t;
        int row = idx4 >> 4, c4 = (idx4 & 15) * 4;
        float4 f = ((const float4*)enc_w)[idx4];
        int off = row * 64 + (((c4 >> 3) ^ (row & 7)) * 8) + (c4 & 7);
        wt[off] = f2bf(f.x); wt[off + 1] = f2bf(f.y);
        wt[off + 2] = f2bf(f.z); wt[off + 3] = f2bf(f.w);
    }
    // stage x rows r0..r0+31
    #pragma unroll
    for (int i = 0; i < 2; ++i) {
        int idx4 = i * 256 + t;
        int row = idx4 >> 4, c4 = (idx4 & 15) * 4;
        float4 f = ((const float4*)(x + (size_t)r0 * D_IN))[idx4];
        int off = row * 64 + (((c4 >> 3) ^ (row & 7)) * 8) + (c4 & 7);
        at[off] = f2bf(f.x); at[off + 1] = f2bf(f.y);
        at[off + 2] = f2bf(f.z); at[off + 3] = f2bf(f.w);
    }
    __syncthreads();

    const int arow = rw * 16 + c16;
    bf16x8 a0 = *(const bf16x8*)(at + arow * 64 + ((g ^ (arow & 7)) * 8));
    bf16x8 a1 = *(const bf16x8*)(at + arow * 64 + (((4 + g) ^ (arow & 7)) * 8));
    f32x4 acc[4];
    #pragma unroll
    for (int sub = 0; sub < 4; ++sub) {
        int bcol = chw * 64 + sub * 16 + c16;
        bf16x8 b0 = *(const bf16x8*)(wt + bcol * 64 + ((g ^ (bcol & 7)) * 8));
        bf16x8 b1 = *(const bf16x8*)(wt + bcol * 64 + (((4 + g) ^ (bcol & 7)) * 8));
        f32x4 z = {0.f, 0.f, 0.f, 0.f};
        z = __builtin_amdgcn_mfma_f32_16x16x32_bf16(a0, b0, z, 0, 0, 0);
        acc[sub] = __builtin_amdgcn_mfma_f32_16x16x32_bf16(a1, b1, z, 0, 0, 0);
    }
    #pragma unroll
    for (int sub = 0; sub < 4; ++sub) {
        int col = chw * 64 + sub * 16 + c16;
        float bias = eb[col];
        #pragma unroll
        for (int rr = 0; rr < 4; ++rr) {
            int row = r0 + rw * 16 + g * 4 + rr;
            float v = fmaxf(acc[sub][rr] + bias, 0.0f);
            h[(size_t)row * H + col] = v;
            h_bf[(size_t)row * H + col] = f2bf(v);
        }
    }
}

// ------- fused q/k/v MFMA, col-split (grid 256): block = 64 rows x 192 cols -------
__global__ __launch_bounds__(256) void qkv_kernel(
    const unsigned short* __restrict__ h_bf, const unsigned short* __restrict__ wqkv_l,
    const float* __restrict__ bqkv_l,
    unsigned short* __restrict__ q, unsigned short* __restrict__ k,
    unsigned short* __restrict__ vT) {
    __shared__ unsigned short wt[192 * 128];
    __shared__ unsigned short at[64 * 128];
    const int t = threadIdx.x;
    const int r0 = (blockIdx.x >> 1) * 64;
    const int ch = blockIdx.x & 1;
    const int w = t >> 6, lane = t & 63, g = lane >> 4, c16 = lane & 15;
    const unsigned short* wsrc = wqkv_l + (size_t)ch * 192 * 128;

    #pragma unroll
    for (int i = 0; i < 12; ++i) {
        int ci = i * 256 + t, row = ci >> 4, cr = ci & 15;
        gload_lds16(wsrc + (size_t)row * 128 + (cr ^ (row & 7)) * 8,
                    (char*)wt + (i * 4 + w) * 1024);
    }
    #pragma unroll
    for (int i = 0; i < 4; ++i) {
        int ci = i * 256 + t, row = ci >> 4, cr = ci & 15;
        gload_lds16(h_bf + (size_t)(r0 + row) * 128 + (cr ^ (row & 7)) * 8,
                    (char*)at + (i * 4 + w) * 1024);
    }
    __syncthreads();

    const int arow = w * 16 + c16;
    bf16x8 a[4];
    #pragma unroll
    for (int ks = 0; ks < 4; ++ks)
        a[ks] = *(const bf16x8*)(at + arow * 128 + (((ks * 4 + g) ^ (arow & 7)) * 8));

    f32x4 acc[12];
    #pragma unroll
    for (int sub = 0; sub < 12; ++sub) {
        int bcol = sub * 16 + c16;
        f32x4 z = {0.f, 0.f, 0.f, 0.f};
        #pragma unroll
        for (int ks = 0; ks < 4; ++ks) {
            bf16x8 bb = *(const bf16x8*)(wt + (size_t)bcol * 128 + (((ks * 4 + g) ^ (bcol & 7)) * 8));
            z = __builtin_amdgcn_mfma_f32_16x16x32_bf16(a[ks], bb, z, 0, 0, 0);
        }
        acc[sub] = z;
    }
    #pragma unroll
    for (int sub = 0; sub < 12; ++sub) {
        int gcol = ch * 192 + sub * 16 + c16;
        int mat = gcol >> 7;
        int colin = gcol & 127;
        float bias = bqkv_l[mat * H + colin];
        if (mat < 2) {
            unsigned short* dst = mat == 0 ? q : k;
            #pragma unroll
            for (int rr = 0; rr < 4; ++rr) {
                int row = r0 + w * 16 + g * 4 + rr;
                dst[(size_t)row * H + colin] = f2bf(acc[sub][rr] + bias);
            }
        } else {
            int hd = colin >> 5, d = colin & 31;
            int bb = r0 >> 10;
            int jbase = (r0 & (N - 1)) + w * 16 + g * 4;
            int pos = (jbase & ~63) + ((((jbase >> 3) & 7) ^ (d & 7)) << 3) + (jbase & 7);
            float v0 = acc[sub][0] + bias, v1 = acc[sub][1] + bias;
            float v2 = acc[sub][2] + bias, v3 = acc[sub][3] + bias;
            unsigned lo, hi;
            asm("v_cvt_pk_bf16_f32 %0, %1, %2" : "=v"(lo) : "v"(v0), "v"(v1));
            asm("v_cvt_pk_bf16_f32 %0, %1, %2" : "=v"(hi) : "v"(v2), "v"(v3));
            uint2 pk2; pk2.x = lo; pk2.y = hi;
            *(uint2*)(vT + ((size_t)(bb * HEADS + hd) * HD + d) * N + pos) = pk2;
        }
    }
}

// ---- swapped-operand MFMA flash attention: 32-row i-tiles, 2 waves, KVBLK=64 ----
// S^T = mfma(K, Q): lane holds S[i = w*16+c16][j = jsub*16+g*4+r], jsub 0..3
// O^T = mfma(V^T, P): lane holds O[i = w*16+c16][d = dsub*16+g*4+r]
__global__ __launch_bounds__(128) void attn_kernel(
    const unsigned short* __restrict__ qg, const unsigned short* __restrict__ kg,
    const unsigned short* __restrict__ vTg, const unsigned* __restrict__ mb,
    float* __restrict__ ao) {
    __shared__ unsigned short qt[32 * 32];      // 2 KB
    __shared__ unsigned short kt[2][64 * 32];   // 8 KB
    __shared__ unsigned short vt[2][32 * 64];   // 8 KB (verbatim copy of stored-swizzled vT)
    __shared__ unsigned short pl[2][16 * 72];   // 4.5 KB

    const int bid = blockIdx.x;
    const int itile = bid & 31;
    const int head = (bid >> 5) & 3;
    const int b = bid >> 7;
    const int i0 = itile * 32;
    const int bh = b * HEADS + head;

    const int t = threadIdx.x;      // 0..127
    const int w = t >> 6;           // 0..1
    const int lane = t & 63;
    const int g = lane >> 4;
    const int c16 = lane & 15;

    const int srow = t >> 2;                    // 0..31
    const int sch = (t & 3) ^ ((t >> 2) & 3);   // K/Q chunk swizzle (key row&3)

    // ---- prologue: Q (once) + K/V^T/mask tile 0 ----
    gload_lds16(qg + ((size_t)(b * N + i0 + srow)) * H + head * HD + sch * 8,
                (char*)qt + w * 1024);
    #pragma unroll
    for (int i = 0; i < 2; ++i)
        gload_lds16(kg + ((size_t)(b * N + i * 32 + srow)) * H + head * HD + sch * 8,
                    (char*)kt[0] + i * 2048 + w * 1024);
    #pragma unroll
    for (int i = 0; i < 2; ++i)
        gload_lds16(vTg + ((size_t)bh * HD + i * 16 + (t >> 3)) * N + (t & 7) * 8,
                    (char*)vt[0] + i * 2048 + w * 1024);

    const unsigned* mrow = mb + (size_t)(b * N + i0 + w * 16 + c16) * (N / 32);
    unsigned long long am = *(const unsigned long long*)mrow;

    __syncthreads();

    const int swq = c16 & 3;
    const bf16x8 qfrag = *(const bf16x8*)(qt + (w * 16 + c16) * 32 + ((g ^ swq) * 8));

    f32x4 oacc[2];
    oacc[0] = (f32x4){0.f, 0.f, 0.f, 0.f};
    oacc[1] = (f32x4){0.f, 0.f, 0.f, 0.f};
    float mrun = NEG_BIG, lrun = 0.0f;

    for (int jt = 0; jt < 16; ++jt) {
        const int cur = jt & 1;
        unsigned long long amn;
        if (jt < 15) {
            const int j0n = (jt + 1) * 64;
            #pragma unroll
            for (int i = 0; i < 2; ++i)
                gload_lds16(kg + ((size_t)(b * N + j0n + i * 32 + srow)) * H + head * HD + sch * 8,
                            (char*)kt[cur ^ 1] + i * 2048 + w * 1024);
            #pragma unroll
            for (int i = 0; i < 2; ++i)
                gload_lds16(vTg + ((size_t)bh * HD + i * 16 + (t >> 3)) * N + j0n + (t & 7) * 8,
                            (char*)vt[cur ^ 1] + i * 2048 + w * 1024);
            amn = *(const unsigned long long*)(mrow + (jt + 1) * 2);
        }
        // ---- S^T (base-2 logits): 4 MFMAs ----
        f32x4 sacc[4];
        __builtin_amdgcn_s_setprio(1);
        #pragma unroll
        for (int jsub = 0; jsub < 4; ++jsub) {
            bf16x8 kfrag = *(const bf16x8*)(kt[cur] + (jsub * 16 + c16) * 32 + ((g ^ swq) * 8));
            f32x4 z = {0.f, 0.f, 0.f, 0.f};
            sacc[jsub] = __builtin_amdgcn_mfma_f32_16x16x32_bf16(kfrag, qfrag, z, 0, 0, 0);
        }
        __builtin_amdgcn_s_setprio(0);
        // ---- mask + per-lane online softmax (row i lane-local) ----
        unsigned long long amg = am >> (g * 4);
        float mx = NEG_BIG;
        #pragma unroll
        for (int jsub = 0; jsub < 4; ++jsub)
            #pragma unroll
            for (int r = 0; r < 4; ++r) {
                bool alive = (amg >> (jsub * 16 + r)) & 1ull;
                float s = alive ? sacc[jsub][r] : NEG_BIG;
                sacc[jsub][r] = s;
                mx = fmaxf(mx, s);
            }
        mx = fmaxf(mx, __shfl_xor(mx, 16));
        mx = fmaxf(mx, __shfl_xor(mx, 32));
        float mnew = fmaxf(mrun, mx);
        float sf = exp2f(mrun - mnew);
        mrun = mnew;
        float rs = 0.0f;
        #pragma unroll
        for (int jsub = 0; jsub < 4; ++jsub)
            #pragma unroll
            for (int r = 0; r < 4; ++r) {
                float pv = exp2f(sacc[jsub][r] - mnew);   // masked -> underflow 0
                sacc[jsub][r] = pv;
                rs += pv;
            }
        rs += __shfl_xor(rs, 16);
        rs += __shfl_xor(rs, 32);
        lrun = lrun * sf + rs;
        // ---- pack P -> per-wave LDS ----
        #pragma unroll
        for (int jsub = 0; jsub < 4; ++jsub) {
            unsigned lo, hi;
            asm("v_cvt_pk_bf16_f32 %0, %1, %2" : "=v"(lo) : "v"(sacc[jsub][0]), "v"(sacc[jsub][1]));
            asm("v_cvt_pk_bf16_f32 %0, %1, %2" : "=v"(hi) : "v"(sacc[jsub][2]), "v"(sacc[jsub][3]));
            uint2 pk2; pk2.x = lo; pk2.y = hi;
            *(uint2*)(&pl[w][c16 * 72 + jsub * 16 + g * 4]) = pk2;
        }
        #pragma unroll
        for (int dsub = 0; dsub < 2; ++dsub)
            #pragma unroll
            for (int r = 0; r < 4; ++r)
                oacc[dsub][r] *= sf;
        asm volatile("s_waitcnt lgkmcnt(0)" ::: "memory");
        // ---- O^T += V^T P : 2 ks x 2 dsub ----
        __builtin_amdgcn_s_setprio(1);
        #pragma unroll
        for (int ks = 0; ks < 2; ++ks) {
            bf16x8 pa = *(const bf16x8*)(&pl[w][c16 * 72 + ks * 32 + g * 8]);
            #pragma unroll
            for (int dsub = 0; dsub < 2; ++dsub) {
                bf16x8 va = *(const bf16x8*)(vt[cur] + (dsub * 16 + c16) * 64 +
                                             (((ks * 4 + g) ^ (c16 & 7)) * 8));
                oacc[dsub] = __builtin_amdgcn_mfma_f32_16x16x32_bf16(va, pa, oacc[dsub], 0, 0, 0);
            }
        }
        __builtin_amdgcn_s_setprio(0);
        if (jt < 15) {
            am = amn;
            __syncthreads();
        }
    }
    // ---- epilogue ----
    float inv = (lrun > 0.0f) ? (1.0f / lrun) : 0.0f;
    #pragma unroll
    for (int dsub = 0; dsub < 2; ++dsub) {
        float4 o;
        o.x = oacc[dsub][0] * inv; o.y = oacc[dsub][1] * inv;
        o.z = oacc[dsub][2] * inv; o.w = oacc[dsub][3] * inv;
        *(float4*)(ao + ((size_t)(b * N + i0 + w * 16 + c16)) * H +
                   head * HD + dsub * 16 + g * 4) = o;
    }
}

// ---- split fp32 32-row tile -> bf16 hi/lo LDS (stride 130) ----
__device__ __forceinline__ void stage_split32(
    const float* __restrict__ src, unsigned short* hi, unsigned short* lo, int t) {
    #pragma unroll
    for (int it = 0; it < 4; ++it) {
        int idx4 = it * 256 + t;
        int row = idx4 >> 5, c4 = (idx4 & 31) * 4;
        float4 f = ((const float4*)src)[idx4];
        unsigned short h0 = f2bf(f.x), h1 = f2bf(f.y), h2 = f2bf(f.z), h3 = f2bf(f.w);
        unsigned short l0 = f2bf(f.x - bf2f(h0)), l1 = f2bf(f.y - bf2f(h1));
        unsigned short l2 = f2bf(f.z - bf2f(h2)), l3 = f2bf(f.w - bf2f(h3));
        *(unsigned*)(hi + row * 130 + c4)     = (unsigned)h0 | ((unsigned)h1 << 16);
        *(unsigned*)(hi + row * 130 + c4 + 2) = (unsigned)h2 | ((unsigned)h3 << 16);
        *(unsigned*)(lo + row * 130 + c4)     = (unsigned)l0 | ((unsigned)l1 << 16);
        *(unsigned*)(lo + row * 130 + c4 + 2) = (unsigned)l2 | ((unsigned)l3 << 16);
    }
}

// ---- 3-term split GEMM, 4 col-subtiles at offset bcol0 ----
__device__ __forceinline__ void split_gemm4(
    const unsigned short* ah, const unsigned short* al,
    const unsigned short* wh, const unsigned short* wl,
    int arow, int g, int c16, int bcol0, f32x4* acc) {
    bf16x8 ahf[4], alf[4];
    #pragma unroll
    for (int ks = 0; ks < 4; ++ks) {
        ahf[ks] = *(const bf16x8*)(ah + arow * 130 + ks * 32 + g * 8);
        alf[ks] = *(const bf16x8*)(al + arow * 130 + ks * 32 + g * 8);
    }
    #pragma unroll
    for (int sub = 0; sub < 4; ++sub) {
        int bcol = bcol0 + sub * 16 + c16;
        f32x4 z = {0.f, 0.f, 0.f, 0.f};
        #pragma unroll
        for (int ks = 0; ks < 4; ++ks) {
            bf16x8 bh = *(const bf16x8*)(wh + bcol * 128 + (((ks * 4 + g) ^ (bcol & 7)) * 8));
            bf16x8 bl = *(const bf16x8*)(wl + bcol * 128 + (((ks * 4 + g) ^ (bcol & 7)) * 8));
            z = __builtin_amdgcn_mfma_f32_16x16x32_bf16(ahf[ks], bh, z, 0, 0, 0);
            z = __builtin_amdgcn_mfma_f32_16x16x32_bf16(alf[ks], bh, z, 0, 0, 0);
            z = __builtin_amdgcn_mfma_f32_16x16x32_bf16(ahf[ks], bl, z, 0, 0, 0);
        }
        acc[sub] = z;
    }
}

__device__ __forceinline__ void stage_w(const unsigned short* __restrict__ src,
                                        unsigned short* dst, int t, int w) {
    #pragma unroll
    for (int i = 0; i < 8; ++i) {
        int ci = i * 256 + t, row = ci >> 4, cr = ci & 15;
        gload_lds16(src + (size_t)row * 128 + (cr ^ (row & 7)) * 8,
                    (char*)dst + (i * 4 + w) * 1024);
    }
}

// ------- layer-0: O-proj + LN + relu + residual, 32-row blocks (grid 256) -------
__global__ __launch_bounds__(256) void oln_kernel(
    const float* __restrict__ ao, const unsigned short* __restrict__ woh_l,
    const unsigned short* __restrict__ wol_l, const float* __restrict__ ob,
    const float* __restrict__ lng, const float* __restrict__ lnb,
    float* __restrict__ h, unsigned short* __restrict__ h_bf) {
    __shared__ unsigned short ah[32 * 130], al[32 * 130];
    __shared__ unsigned short wh[128 * 128], wl[128 * 128];
    __shared__ float red1[2][32], red2[2][32];
    const int t = threadIdx.x;
    const int r0 = blockIdx.x * 32;
    const int w = t >> 6, lane = t & 63, g = lane >> 4, c16 = lane & 15;
    const int rw = w & 1, chw = w >> 1;

    stage_w(woh_l, wh, t, w);
    stage_w(wol_l, wl, t, w);
    stage_split32(ao + (size_t)r0 * H, ah, al, t);
    __syncthreads();

    const int arow = rw * 16 + c16;
    f32x4 acc[4];
    split_gemm4(ah, al, wh, wl, arow, g, c16, chw * 64, acc);

    float val[4][4], s1[4] = {0, 0, 0, 0}, s2[4] = {0, 0, 0, 0};
    #pragma unroll
    for (int sub = 0; sub < 4; ++sub) {
        int col = chw * 64 + sub * 16 + c16;
        float bias = ob[col];
        #pragma unroll
        for (int rr = 0; rr < 4; ++rr) {
            float vv = acc[sub][rr] + bias;
            val[sub][rr] = vv;
            s1[rr] += vv;
            s2[rr] += vv * vv;
        }
    }
    #pragma unroll
    for (int rr = 0; rr < 4; ++rr) {
        #pragma unroll
        for (int off = 1; off < 16; off <<= 1) {
            s1[rr] += __shfl_xor(s1[rr], off);
            s2[rr] += __shfl_xor(s2[rr], off);
        }
    }
    if (c16 == 0) {
        #pragma unroll
        for (int rr = 0; rr < 4; ++rr) {
            red1[chw][rw * 16 + g * 4 + rr] = s1[rr];
            red2[chw][rw * 16 + g * 4 + rr] = s2[rr];
        }
    }
    __syncthreads();
    #pragma unroll
    for (int rr = 0; rr < 4; ++rr) {
        int rl = rw * 16 + g * 4 + rr;
        float t1 = red1[0][rl] + red1[1][rl];
        float t2 = red2[0][rl] + red2[1][rl];
        float mu = t1 * (1.0f / H);
        float var = t2 * (1.0f / H) - mu * mu;
        float rsn = rsqrtf(var + EPS);
        int row = r0 + rl;
        #pragma unroll
        for (int sub = 0; sub < 4; ++sub) {
            int col = chw * 64 + sub * 16 + c16;
            float y = (val[sub][rr] - mu) * rsn * lng[col] + lnb[col];
            float hn = fmaxf(y, 0.0f) + h[(size_t)row * H + col];
            h[(size_t)row * H + col] = hn;
            h_bf[(size_t)row * H + col] = f2bf(hn);
        }
    }
}

// ------- layer-1 fused: O-proj + LN + relu + residual + final proj, 32-row blocks -------
__global__ __launch_bounds__(256) void olnfinal_kernel(
    const float* __restrict__ ao, const unsigned short* __restrict__ woh_l,
    const unsigned short* __restrict__ wol_l, const float* __restrict__ ob,
    const float* __restrict__ lng, const float* __restrict__ lnb,
    const float* __restrict__ h, const unsigned short* __restrict__ wfh,
    const unsigned short* __restrict__ wfl, const float* __restrict__ fb,
    float* __restrict__ out) {
    __shared__ unsigned short ah[32 * 130], al[32 * 130];
    __shared__ unsigned short wh[128 * 128], wl[128 * 128];
    __shared__ float red1[2][32], red2[2][32];
    const int t = threadIdx.x;
    const int r0 = blockIdx.x * 32;
    const int w = t >> 6, lane = t & 63, g = lane >> 4, c16 = lane & 15;
    const int rw = w & 1, chw = w >> 1;

    stage_w(woh_l, wh, t, w);
    stage_w(wol_l, wl, t, w);
    stage_split32(ao + (size_t)r0 * H, ah, al, t);
    __syncthreads();

    const int arow = rw * 16 + c16;
    f32x4 acc[4];
    split_gemm4(ah, al, wh, wl, arow, g, c16, chw * 64, acc);

    float val[4][4], s1[4] = {0, 0, 0, 0}, s2[4] = {0, 0, 0, 0};
    #pragma unroll
    for (int sub = 0; sub < 4; ++sub) {
        int col = chw * 64 + sub * 16 + c16;
        float bias = ob[col];
        #pragma unroll
        for (int rr = 0; rr < 4; ++rr) {
            float vv = acc[sub][rr] + bias;
            val[sub][rr] = vv;
            s1[rr] += vv;
            s2[rr] += vv * vv;
        }
    }
    #pragma unroll
    for (int rr = 0; rr < 4; ++rr) {
        #pragma unroll
        for (int off = 1; off < 16; off <<= 1) {
            s1[rr] += __shfl_xor(s1[rr], off);
            s2[rr] += __shfl_xor(s2[rr], off);
        }
    }
    if (c16 == 0) {
        #pragma unroll
        for (int rr = 0; rr < 4; ++rr) {
            red1[chw][rw * 16 + g * 4 + rr] = s1[rr];
            red2[chw][rw * 16 + g * 4 + rr] = s2[rr];
        }
    }
    __syncthreads();   // red ready; all ah/al/wh/wl reads complete
    #pragma unroll
    for (int rr = 0; rr < 4; ++rr) {
        int rl = rw * 16 + g * 4 + rr;
        float t1 = red1[0][rl] + red1[1][rl];
        float t2 = red2[0][rl] + red2[1][rl];
        float mu = t1 * (1.0f / H);
        float var = t2 * (1.0f / H) - mu * mu;
        float rsn = rsqrtf(var + EPS);
        #pragma unroll
        for (int sub = 0; sub < 4; ++sub) {
            int col = chw * 64 + sub * 16 + c16;
            float y = (val[sub][rr] - mu) * rsn * lng[col] + lnb[col];
            float hn = fmaxf(y, 0.0f) + h[(size_t)(r0 + rl) * H + col];
            unsigned short hi = f2bf(hn);
            ah[rl * 130 + col] = hi;
            al[rl * 130 + col] = f2bf(hn - bf2f(hi));
        }
    }
    stage_w(wfh, wh, t, w);
    stage_w(wfl, wl, t, w);
    __syncthreads();

    f32x4 fac[4];
    split_gemm4(ah, al, wh, wl, arow, g, c16, chw * 64, fac);
    #pragma unroll
    for (int sub = 0; sub < 4; ++sub) {
        int col = chw * 64 + sub * 16 + c16;
        float bias = fb[col];
        #pragma unroll
        for (int rr = 0; rr < 4; ++rr) {
            int row = r0 + rw * 16 + g * 4 + rr;
            out[(size_t)row * H + col] = fac[sub][rr] + bias;
        }
    }
}

extern "C" void kernel_launch(void* const* d_in, const int* in_sizes, int n_in,
                              void* d_out, int out_size, void* d_ws, size_t ws_size,
                              hipStream_t stream) {
    const float* x     = (const float*)d_in[0];
    const float* adj   = (const float*)d_in[1];
    const float* enc_w = (const float*)d_in[2];
    const float* enc_b = (const float*)d_in[3];
    const float* q_w   = (const float*)d_in[4];
    const float* q_b   = (const float*)d_in[5];
    const float* k_w   = (const float*)d_in[6];
    const float* k_b   = (const float*)d_in[7];
    const float* v_w   = (const float*)d_in[8];
    const float* v_b   = (const float*)d_in[9];
    const float* o_w   = (const float*)d_in[10];
    const float* o_b   = (const float*)d_in[11];
    const float* ln_g  = (const float*)d_in[12];
    const float* ln_b  = (const float*)d_in[13];
    const float* out_w = (const float*)d_in[14];
    const float* out_b = (const float*)d_in[15];

    const size_t BNH = (size_t)B * N * H;
    float* h  = (float*)d_ws;
    float* ao = h + BNH;
    unsigned short* h_bf = (unsigned short*)(ao + BNH);
    unsigned short* qb = h_bf + BNH;
    unsigned short* kb = qb + BNH;
    unsigned short* vT = kb + BNH;
    unsigned* mbits = (unsigned*)(vT + BNH);
    unsigned short* wqkv = (unsigned short*)(mbits + (size_t)B * N * N / 32);
    float* bqkv = (float*)(wqkv + (size_t)L * 3 * H * H);
    unsigned short* woh = (unsigned short*)(bqkv + L * 3 * H);
    unsigned short* wol = woh + (size_t)L * H * H;
    unsigned short* wfh = wol + (size_t)L * H * H;
    unsigned short* wfl = wfh + (size_t)H * H;

    front_kernel<<<NPACK + NPREP + NENC, 256, 0, stream>>>(
        adj, x, enc_w, enc_b, q_w, k_w, v_w, q_b, k_b, v_b, o_w, out_w,
        mbits, wqkv, bqkv, woh, wol, wfh, wfl, h, h_bf);

    // layer 0
    qkv_kernel<<<B * N / 32, 256, 0, stream>>>(h_bf, wqkv, bqkv, qb, kb, vT);
    attn_kernel<<<B * HEADS * (N / 32), 128, 0, stream>>>(qb, kb, vT, mbits, ao);
    oln_kernel<<<B * N / 32, 256, 0, stream>>>(
        ao, woh, wol, o_b, ln_g, ln_b, h, h_bf);
    // layer 1 (+ final fused)
    qkv_kernel<<<B * N / 32, 256, 0, stream>>>(
        h_bf, wqkv + (size_t)3 * H * H, bqkv + 3 * H, qb, kb, vT);
    attn_kernel<<<B * HEADS * (N / 32), 128, 0, stream>>>(qb, kb, vT, mbits, ao);
    olnfinal_kernel<<<B * N / 32, 256, 0, stream>>>(
        ao, woh + (size_t)H * H, wol + (size_t)H * H, o_b + H,
        ln_g + H, ln_b + H, h, wfh, wfl, out_b, (float*)d_out);
}

// Round 12
// 91.656 us; speedup vs baseline: 1.0891x; 1.0891x over previous
//
#include <hip/hip_runtime.h>

#define B 8
#define N 1024
#define D_IN 64
#define H 128
#define HEADS 4
#define HD 32
#define L 2
#define EPS 1e-5f
#define NEG_BIG -1e30f
// 1/sqrt(32) * log2(e): softmax computed in base-2 domain (exp2f)
#define QSCALE (0.17677669529663687f * 1.4426950408889634f)

typedef __attribute__((ext_vector_type(8))) short bf16x8;
typedef __attribute__((ext_vector_type(4))) float f32x4;

__device__ __forceinline__ unsigned short f2bf(float f) {
    unsigned u = __float_as_uint(f);
    u = u + 0x7fffu + ((u >> 16) & 1u);
    return (unsigned short)(u >> 16);
}
__device__ __forceinline__ float bf2f(unsigned short s) {
    return __uint_as_float(((unsigned)s) << 16);
}
__device__ __forceinline__ void gload_lds16(const void* g, void* l) {
    __builtin_amdgcn_global_load_lds(
        (const __attribute__((address_space(1))) unsigned int*)g,
        (__attribute__((address_space(3))) unsigned int*)l,
        16, 0, 0);
}

#define NPACK 1024           // B*N*N/32/256
#define NPREP 579            // (L*3*H*H + L*3*H + L*H*H + H*H)/256
#define NENC  256            // B*N/32

// ======== fused front: adj-pack | weight-prep | encoder (independent roles) ========
__global__ __launch_bounds__(256) void front_kernel(
    const float* __restrict__ adj, const float* __restrict__ x,
    const float* __restrict__ enc_w, const float* __restrict__ eb,
    const float* __restrict__ q_w, const float* __restrict__ k_w,
    const float* __restrict__ v_w, const float* __restrict__ q_b,
    const float* __restrict__ k_b, const float* __restrict__ v_b,
    const float* __restrict__ o_w, const float* __restrict__ out_w,
    unsigned* __restrict__ mb, unsigned short* __restrict__ wqkv,
    float* __restrict__ bqkv, unsigned short* __restrict__ woh,
    unsigned short* __restrict__ wol, unsigned short* __restrict__ wfh,
    unsigned short* __restrict__ wfl, float* __restrict__ h,
    unsigned short* __restrict__ h_bf) {
    __shared__ unsigned short wt[H * D_IN];    // 16 KB (enc role only)
    __shared__ unsigned short at[32 * D_IN];   // 4 KB
    const int blk = blockIdx.x;
    const int t = threadIdx.x;

    if (blk < NPACK) {                 // ---- adj -> bitmask ----
        int wd = blk * 256 + t;
        const float4* src = (const float4*)(adj + (size_t)wd * 32);
        unsigned m = 0;
        #pragma unroll
        for (int c = 0; c < 8; ++c) {
            float4 f = src[c];
            if (f.x != 0.0f) m |= 1u << (c * 4 + 0);
            if (f.y != 0.0f) m |= 1u << (c * 4 + 1);
            if (f.z != 0.0f) m |= 1u << (c * 4 + 2);
            if (f.w != 0.0f) m |= 1u << (c * 4 + 3);
        }
        mb[wd] = m;
        return;
    }
    if (blk < NPACK + NPREP) {         // ---- weight prep ----
        int id = (blk - NPACK) * 256 + t;
        const int WQ = L * 3 * H * H;
        const int BQ = L * 3 * H;
        const int WO = L * H * H;
        if (id < WQ) {
            int layer = id / (3 * H * H);
            int r = id % (3 * H * H);
            int mat = r / (H * H);
            int e = r % (H * H);
            const float* src = mat == 0 ? q_w : (mat == 1 ? k_w : v_w);
            float f = src[layer * H * H + e];
            if (mat == 0) f *= QSCALE;
            wqkv[id] = f2bf(f);
            return;
        }
        id -= WQ;
        if (id < BQ) {
            int layer = id / (3 * H);
            int r = id % (3 * H);
            int mat = r / H;
            int e = r % H;
            const float* src = mat == 0 ? q_b : (mat == 1 ? k_b : v_b);
            float f = src[layer * H + e];
            if (mat == 0) f *= QSCALE;
            bqkv[id] = f;
            return;
        }
        id -= BQ;
        if (id < WO) {
            float f = o_w[id];
            unsigned short hi = f2bf(f);
            woh[id] = hi;
            wol[id] = f2bf(f - bf2f(hi));
            return;
        }
        id -= WO;
        {
            float f = out_w[id];
            unsigned short hi = f2bf(f);
            wfh[id] = hi;
            wfl[id] = f2bf(f - bf2f(hi));
        }
        return;
    }
    // ---- encoder: h = relu(x @ enc_w.T + b), 32-row blocks, in-kernel bf16 convert ----
    const int r0 = (blk - NPACK - NPREP) * 32;
    const int w = t >> 6, lane = t & 63, g = lane >> 4, c16 = lane & 15;
    const int rw = w & 1, chw = w >> 1;

    // stage enc_w (128x64) fp32 -> bf16 LDS, chunk-swizzled (key row&7)
    #pragma unroll
    for (int i = 0; i < 8; ++i) {
        int idx4 = i * 256 + t;
        int row = idx4 >> 4, c4 = (idx4 & 15) * 4;
        float4 f = ((const float4*)enc_w)[idx4];
        int off = row * 64 + (((c4 >> 3) ^ (row & 7)) * 8) + (c4 & 7);
        wt[off] = f2bf(f.x); wt[off + 1] = f2bf(f.y);
        wt[off + 2] = f2bf(f.z); wt[off + 3] = f2bf(f.w);
    }
    // stage x rows r0..r0+31
    #pragma unroll
    for (int i = 0; i < 2; ++i) {
        int idx4 = i * 256 + t;
        int row = idx4 >> 4, c4 = (idx4 & 15) * 4;
        float4 f = ((const float4*)(x + (size_t)r0 * D_IN))[idx4];
        int off = row * 64 + (((c4 >> 3) ^ (row & 7)) * 8) + (c4 & 7);
        at[off] = f2bf(f.x); at[off + 1] = f2bf(f.y);
        at[off + 2] = f2bf(f.z); at[off + 3] = f2bf(f.w);
    }
    __syncthreads();

    const int arow = rw * 16 + c16;
    bf16x8 a0 = *(const bf16x8*)(at + arow * 64 + ((g ^ (arow & 7)) * 8));
    bf16x8 a1 = *(const bf16x8*)(at + arow * 64 + (((4 + g) ^ (arow & 7)) * 8));
    f32x4 acc[4];
    #pragma unroll
    for (int sub = 0; sub < 4; ++sub) {
        int bcol = chw * 64 + sub * 16 + c16;
        bf16x8 b0 = *(const bf16x8*)(wt + bcol * 64 + ((g ^ (bcol & 7)) * 8));
        bf16x8 b1 = *(const bf16x8*)(wt + bcol * 64 + (((4 + g) ^ (bcol & 7)) * 8));
        f32x4 z = {0.f, 0.f, 0.f, 0.f};
        z = __builtin_amdgcn_mfma_f32_16x16x32_bf16(a0, b0, z, 0, 0, 0);
        acc[sub] = __builtin_amdgcn_mfma_f32_16x16x32_bf16(a1, b1, z, 0, 0, 0);
    }
    #pragma unroll
    for (int sub = 0; sub < 4; ++sub) {
        int col = chw * 64 + sub * 16 + c16;
        float bias = eb[col];
        #pragma unroll
        for (int rr = 0; rr < 4; ++rr) {
            int row = r0 + rw * 16 + g * 4 + rr;
            float v = fmaxf(acc[sub][rr] + bias, 0.0f);
            h[(size_t)row * H + col] = v;
            h_bf[(size_t)row * H + col] = f2bf(v);
        }
    }
}

// ------- fused q/k/v MFMA, col-split (grid 256): block = 64 rows x 192 cols -------
__global__ __launch_bounds__(256) void qkv_kernel(
    const unsigned short* __restrict__ h_bf, const unsigned short* __restrict__ wqkv_l,
    const float* __restrict__ bqkv_l,
    unsigned short* __restrict__ q, unsigned short* __restrict__ k,
    unsigned short* __restrict__ vT) {
    __shared__ unsigned short wt[192 * 128];
    __shared__ unsigned short at[64 * 128];
    const int t = threadIdx.x;
    const int r0 = (blockIdx.x >> 1) * 64;
    const int ch = blockIdx.x & 1;
    const int w = t >> 6, lane = t & 63, g = lane >> 4, c16 = lane & 15;
    const unsigned short* wsrc = wqkv_l + (size_t)ch * 192 * 128;

    #pragma unroll
    for (int i = 0; i < 12; ++i) {
        int ci = i * 256 + t, row = ci >> 4, cr = ci & 15;
        gload_lds16(wsrc + (size_t)row * 128 + (cr ^ (row & 7)) * 8,
                    (char*)wt + (i * 4 + w) * 1024);
    }
    #pragma unroll
    for (int i = 0; i < 4; ++i) {
        int ci = i * 256 + t, row = ci >> 4, cr = ci & 15;
        gload_lds16(h_bf + (size_t)(r0 + row) * 128 + (cr ^ (row & 7)) * 8,
                    (char*)at + (i * 4 + w) * 1024);
    }
    __syncthreads();

    const int arow = w * 16 + c16;
    bf16x8 a[4];
    #pragma unroll
    for (int ks = 0; ks < 4; ++ks)
        a[ks] = *(const bf16x8*)(at + arow * 128 + (((ks * 4 + g) ^ (arow & 7)) * 8));

    f32x4 acc[12];
    #pragma unroll
    for (int sub = 0; sub < 12; ++sub) {
        int bcol = sub * 16 + c16;
        f32x4 z = {0.f, 0.f, 0.f, 0.f};
        #pragma unroll
        for (int ks = 0; ks < 4; ++ks) {
            bf16x8 bb = *(const bf16x8*)(wt + (size_t)bcol * 128 + (((ks * 4 + g) ^ (bcol & 7)) * 8));
            z = __builtin_amdgcn_mfma_f32_16x16x32_bf16(a[ks], bb, z, 0, 0, 0);
        }
        acc[sub] = z;
    }
    #pragma unroll
    for (int sub = 0; sub < 12; ++sub) {
        int gcol = ch * 192 + sub * 16 + c16;
        int mat = gcol >> 7;
        int colin = gcol & 127;
        float bias = bqkv_l[mat * H + colin];
        if (mat < 2) {
            unsigned short* dst = mat == 0 ? q : k;
            #pragma unroll
            for (int rr = 0; rr < 4; ++rr) {
                int row = r0 + w * 16 + g * 4 + rr;
                dst[(size_t)row * H + colin] = f2bf(acc[sub][rr] + bias);
            }
        } else {
            int hd = colin >> 5, d = colin & 31;
            int bb = r0 >> 10;
            int jbase = (r0 & (N - 1)) + w * 16 + g * 4;
            int pos = (jbase & ~63) + ((((jbase >> 3) & 7) ^ (d & 7)) << 3) + (jbase & 7);
            float v0 = acc[sub][0] + bias, v1 = acc[sub][1] + bias;
            float v2 = acc[sub][2] + bias, v3 = acc[sub][3] + bias;
            unsigned lo, hi;
            asm("v_cvt_pk_bf16_f32 %0, %1, %2" : "=v"(lo) : "v"(v0), "v"(v1));
            asm("v_cvt_pk_bf16_f32 %0, %1, %2" : "=v"(hi) : "v"(v2), "v"(v3));
            uint2 pk2; pk2.x = lo; pk2.y = hi;
            *(uint2*)(vT + ((size_t)(bb * HEADS + hd) * HD + d) * N + pos) = pk2;
        }
    }
}

// ---------------- swapped-operand MFMA flash attention, KVBLK=128, exp2 domain ----------------
// (reverted to the R9/R10-proven 256-thread shape)
__global__ __launch_bounds__(256) void attn_kernel(
    const unsigned short* __restrict__ qg, const unsigned short* __restrict__ kg,
    const unsigned short* __restrict__ vTg, const unsigned* __restrict__ mb,
    float* __restrict__ ao) {
    __shared__ unsigned short qt[64 * 32];
    __shared__ unsigned short kt[2][128 * 32];
    __shared__ unsigned short vt[2][32 * 128];
    __shared__ unsigned short pl[4][16 * 136];

    const int bid = blockIdx.x;
    const int itile = bid & 15;
    const int head = (bid >> 4) & 3;
    const int b = bid >> 6;
    const int i0 = itile * 64;
    const int bh = b * HEADS + head;

    const int t = threadIdx.x;
    const int w = t >> 6;
    const int lane = t & 63;
    const int g = lane >> 4;
    const int c16 = lane & 15;

    const int srow = t >> 2;
    const int sch = (t & 3) ^ ((t >> 2) & 3);

    gload_lds16(qg + ((size_t)(b * N + i0 + srow)) * H + head * HD + sch * 8,
                (char*)qt + w * 1024);
    #pragma unroll
    for (int i = 0; i < 2; ++i)
        gload_lds16(kg + ((size_t)(b * N + i * 64 + srow)) * H + head * HD + sch * 8,
                    (char*)kt[0] + i * 4096 + w * 1024);
    #pragma unroll
    for (int i = 0; i < 2; ++i) {
        int d = i * 16 + (t >> 4), c = t & 15;
        gload_lds16(vTg + ((size_t)bh * HD + d) * N + c * 8,
                    (char*)vt[0] + i * 4096 + w * 1024);
    }
    const unsigned* mrow = mb + (size_t)(b * N + i0 + w * 16 + c16) * (N / 32);
    uint4 am = *(const uint4*)mrow;

    __syncthreads();

    const int swq = c16 & 3;
    const bf16x8 qfrag = *(const bf16x8*)(qt + (w * 16 + c16) * 32 + ((g ^ swq) * 8));

    f32x4 oacc[2];
    oacc[0] = (f32x4){0.f, 0.f, 0.f, 0.f};
    oacc[1] = (f32x4){0.f, 0.f, 0.f, 0.f};
    float mrun = NEG_BIG, lrun = 0.0f;

    for (int jt = 0; jt < 8; ++jt) {
        const int cur = jt & 1;
        uint4 amn;
        if (jt < 7) {
            const int j0n = (jt + 1) * 128;
            #pragma unroll
            for (int i = 0; i < 2; ++i)
                gload_lds16(kg + ((size_t)(b * N + j0n + i * 64 + srow)) * H + head * HD + sch * 8,
                            (char*)kt[cur ^ 1] + i * 4096 + w * 1024);
            #pragma unroll
            for (int i = 0; i < 2; ++i) {
                int d = i * 16 + (t >> 4), c = t & 15;
                gload_lds16(vTg + ((size_t)bh * HD + d) * N + j0n + c * 8,
                            (char*)vt[cur ^ 1] + i * 4096 + w * 1024);
            }
            amn = *(const uint4*)(mrow + (jt + 1) * 4);
        }
        // ---- S^T (base-2 logits): 8 MFMAs ----
        f32x4 sacc[8];
        __builtin_amdgcn_s_setprio(1);
        #pragma unroll
        for (int jsub = 0; jsub < 8; ++jsub) {
            bf16x8 kfrag = *(const bf16x8*)(kt[cur] + (jsub * 16 + c16) * 32 + ((g ^ swq) * 8));
            f32x4 z = {0.f, 0.f, 0.f, 0.f};
            sacc[jsub] = __builtin_amdgcn_mfma_f32_16x16x32_bf16(kfrag, qfrag, z, 0, 0, 0);
        }
        __builtin_amdgcn_s_setprio(0);
        // ---- mask + per-lane online softmax ----
        float mx = NEG_BIG;
        #pragma unroll
        for (int jsub = 0; jsub < 8; ++jsub) {
            int wsel = jsub >> 1;
            unsigned mw = wsel == 0 ? am.x : wsel == 1 ? am.y : wsel == 2 ? am.z : am.w;
            #pragma unroll
            for (int r = 0; r < 4; ++r) {
                bool alive = (mw >> ((jsub & 1) * 16 + g * 4 + r)) & 1u;
                float s = alive ? sacc[jsub][r] : NEG_BIG;
                sacc[jsub][r] = s;
                mx = fmaxf(mx, s);
            }
        }
        mx = fmaxf(mx, __shfl_xor(mx, 16));
        mx = fmaxf(mx, __shfl_xor(mx, 32));
        float mnew = fmaxf(mrun, mx);
        float sf = exp2f(mrun - mnew);
        mrun = mnew;
        float rs = 0.0f;
        #pragma unroll
        for (int jsub = 0; jsub < 8; ++jsub)
            #pragma unroll
            for (int r = 0; r < 4; ++r) {
                float pv = exp2f(sacc[jsub][r] - mnew);   // masked -> underflow 0
                sacc[jsub][r] = pv;
                rs += pv;
            }
        rs += __shfl_xor(rs, 16);
        rs += __shfl_xor(rs, 32);
        lrun = lrun * sf + rs;
        // ---- pack P -> per-wave LDS ----
        #pragma unroll
        for (int jsub = 0; jsub < 8; ++jsub) {
            unsigned lo, hi;
            asm("v_cvt_pk_bf16_f32 %0, %1, %2" : "=v"(lo) : "v"(sacc[jsub][0]), "v"(sacc[jsub][1]));
            asm("v_cvt_pk_bf16_f32 %0, %1, %2" : "=v"(hi) : "v"(sacc[jsub][2]), "v"(sacc[jsub][3]));
            uint2 pk2; pk2.x = lo; pk2.y = hi;
            *(uint2*)(&pl[w][c16 * 136 + jsub * 16 + g * 4]) = pk2;
        }
        #pragma unroll
        for (int dsub = 0; dsub < 2; ++dsub)
            #pragma unroll
            for (int r = 0; r < 4; ++r)
                oacc[dsub][r] *= sf;
        asm volatile("s_waitcnt lgkmcnt(0)" ::: "memory");
        // ---- O^T += V^T P ----
        __builtin_amdgcn_s_setprio(1);
        #pragma unroll
        for (int ks = 0; ks < 4; ++ks) {
            bf16x8 pa = *(const bf16x8*)(&pl[w][c16 * 136 + ks * 32 + g * 8]);
            #pragma unroll
            for (int dsub = 0; dsub < 2; ++dsub) {
                int cj = ks * 4 + g;
                bf16x8 va = *(const bf16x8*)(vt[cur] + (dsub * 16 + c16) * 128 +
                                             (cj >> 3) * 64 + (((cj & 7) ^ (c16 & 7)) * 8));
                oacc[dsub] = __builtin_amdgcn_mfma_f32_16x16x32_bf16(va, pa, oacc[dsub], 0, 0, 0);
            }
        }
        __builtin_amdgcn_s_setprio(0);
        if (jt < 7) {
            am = amn;
            __syncthreads();
        }
    }
    float inv = (lrun > 0.0f) ? (1.0f / lrun) : 0.0f;
    #pragma unroll
    for (int dsub = 0; dsub < 2; ++dsub) {
        float4 o;
        o.x = oacc[dsub][0] * inv; o.y = oacc[dsub][1] * inv;
        o.z = oacc[dsub][2] * inv; o.w = oacc[dsub][3] * inv;
        *(float4*)(ao + ((size_t)(b * N + i0 + w * 16 + c16)) * H +
                   head * HD + dsub * 16 + g * 4) = o;
    }
}

// ---- split fp32 32-row tile -> bf16 hi/lo LDS (stride 130) ----
__device__ __forceinline__ void stage_split32(
    const float* __restrict__ src, unsigned short* hi, unsigned short* lo, int t) {
    #pragma unroll
    for (int it = 0; it < 4; ++it) {
        int idx4 = it * 256 + t;
        int row = idx4 >> 5, c4 = (idx4 & 31) * 4;
        float4 f = ((const float4*)src)[idx4];
        unsigned short h0 = f2bf(f.x), h1 = f2bf(f.y), h2 = f2bf(f.z), h3 = f2bf(f.w);
        unsigned short l0 = f2bf(f.x - bf2f(h0)), l1 = f2bf(f.y - bf2f(h1));
        unsigned short l2 = f2bf(f.z - bf2f(h2)), l3 = f2bf(f.w - bf2f(h3));
        *(unsigned*)(hi + row * 130 + c4)     = (unsigned)h0 | ((unsigned)h1 << 16);
        *(unsigned*)(hi + row * 130 + c4 + 2) = (unsigned)h2 | ((unsigned)h3 << 16);
        *(unsigned*)(lo + row * 130 + c4)     = (unsigned)l0 | ((unsigned)l1 << 16);
        *(unsigned*)(lo + row * 130 + c4 + 2) = (unsigned)l2 | ((unsigned)l3 << 16);
    }
}

// ---- 3-term split GEMM, 4 col-subtiles at offset bcol0 ----
__device__ __forceinline__ void split_gemm4(
    const unsigned short* ah, const unsigned short* al,
    const unsigned short* wh, const unsigned short* wl,
    int arow, int g, int c16, int bcol0, f32x4* acc) {
    bf16x8 ahf[4], alf[4];
    #pragma unroll
    for (int ks = 0; ks < 4; ++ks) {
        ahf[ks] = *(const bf16x8*)(ah + arow * 130 + ks * 32 + g * 8);
        alf[ks] = *(const bf16x8*)(al + arow * 130 + ks * 32 + g * 8);
    }
    #pragma unroll
    for (int sub = 0; sub < 4; ++sub) {
        int bcol = bcol0 + sub * 16 + c16;
        f32x4 z = {0.f, 0.f, 0.f, 0.f};
        #pragma unroll
        for (int ks = 0; ks < 4; ++ks) {
            bf16x8 bh = *(const bf16x8*)(wh + bcol * 128 + (((ks * 4 + g) ^ (bcol & 7)) * 8));
            bf16x8 bl = *(const bf16x8*)(wl + bcol * 128 + (((ks * 4 + g) ^ (bcol & 7)) * 8));
            z = __builtin_amdgcn_mfma_f32_16x16x32_bf16(ahf[ks], bh, z, 0, 0, 0);
            z = __builtin_amdgcn_mfma_f32_16x16x32_bf16(alf[ks], bh, z, 0, 0, 0);
            z = __builtin_amdgcn_mfma_f32_16x16x32_bf16(ahf[ks], bl, z, 0, 0, 0);
        }
        acc[sub] = z;
    }
}

__device__ __forceinline__ void stage_w(const unsigned short* __restrict__ src,
                                        unsigned short* dst, int t, int w) {
    #pragma unroll
    for (int i = 0; i < 8; ++i) {
        int ci = i * 256 + t, row = ci >> 4, cr = ci & 15;
        gload_lds16(src + (size_t)row * 128 + (cr ^ (row & 7)) * 8,
                    (char*)dst + (i * 4 + w) * 1024);
    }
}

// ------- layer-0: O-proj + LN + relu + residual, 32-row blocks (grid 256) -------
__global__ __launch_bounds__(256) void oln_kernel(
    const float* __restrict__ ao, const unsigned short* __restrict__ woh_l,
    const unsigned short* __restrict__ wol_l, const float* __restrict__ ob,
    const float* __restrict__ lng, const float* __restrict__ lnb,
    float* __restrict__ h, unsigned short* __restrict__ h_bf) {
    __shared__ unsigned short ah[32 * 130], al[32 * 130];
    __shared__ unsigned short wh[128 * 128], wl[128 * 128];
    __shared__ float red1[2][32], red2[2][32];
    const int t = threadIdx.x;
    const int r0 = blockIdx.x * 32;
    const int w = t >> 6, lane = t & 63, g = lane >> 4, c16 = lane & 15;
    const int rw = w & 1, chw = w >> 1;

    stage_w(woh_l, wh, t, w);
    stage_w(wol_l, wl, t, w);
    stage_split32(ao + (size_t)r0 * H, ah, al, t);
    __syncthreads();

    const int arow = rw * 16 + c16;
    f32x4 acc[4];
    split_gemm4(ah, al, wh, wl, arow, g, c16, chw * 64, acc);

    float val[4][4], s1[4] = {0, 0, 0, 0}, s2[4] = {0, 0, 0, 0};
    #pragma unroll
    for (int sub = 0; sub < 4; ++sub) {
        int col = chw * 64 + sub * 16 + c16;
        float bias = ob[col];
        #pragma unroll
        for (int rr = 0; rr < 4; ++rr) {
            float vv = acc[sub][rr] + bias;
            val[sub][rr] = vv;
            s1[rr] += vv;
            s2[rr] += vv * vv;
        }
    }
    #pragma unroll
    for (int rr = 0; rr < 4; ++rr) {
        #pragma unroll
        for (int off = 1; off < 16; off <<= 1) {
            s1[rr] += __shfl_xor(s1[rr], off);
            s2[rr] += __shfl_xor(s2[rr], off);
        }
    }
    if (c16 == 0) {
        #pragma unroll
        for (int rr = 0; rr < 4; ++rr) {
            red1[chw][rw * 16 + g * 4 + rr] = s1[rr];
            red2[chw][rw * 16 + g * 4 + rr] = s2[rr];
        }
    }
    __syncthreads();
    #pragma unroll
    for (int rr = 0; rr < 4; ++rr) {
        int rl = rw * 16 + g * 4 + rr;
        float t1 = red1[0][rl] + red1[1][rl];
        float t2 = red2[0][rl] + red2[1][rl];
        float mu = t1 * (1.0f / H);
        float var = t2 * (1.0f / H) - mu * mu;
        float rsn = rsqrtf(var + EPS);
        int row = r0 + rl;
        #pragma unroll
        for (int sub = 0; sub < 4; ++sub) {
            int col = chw * 64 + sub * 16 + c16;
            float y = (val[sub][rr] - mu) * rsn * lng[col] + lnb[col];
            float hn = fmaxf(y, 0.0f) + h[(size_t)row * H + col];
            h[(size_t)row * H + col] = hn;
            h_bf[(size_t)row * H + col] = f2bf(hn);
        }
    }
}

// ------- layer-1 fused: O-proj + LN + relu + residual + final proj, 32-row blocks -------
__global__ __launch_bounds__(256) void olnfinal_kernel(
    const float* __restrict__ ao, const unsigned short* __restrict__ woh_l,
    const unsigned short* __restrict__ wol_l, const float* __restrict__ ob,
    const float* __restrict__ lng, const float* __restrict__ lnb,
    const float* __restrict__ h, const unsigned short* __restrict__ wfh,
    const unsigned short* __restrict__ wfl, const float* __restrict__ fb,
    float* __restrict__ out) {
    __shared__ unsigned short ah[32 * 130], al[32 * 130];
    __shared__ unsigned short wh[128 * 128], wl[128 * 128];
    __shared__ float red1[2][32], red2[2][32];
    const int t = threadIdx.x;
    const int r0 = blockIdx.x * 32;
    const int w = t >> 6, lane = t & 63, g = lane >> 4, c16 = lane & 15;
    const int rw = w & 1, chw = w >> 1;

    stage_w(woh_l, wh, t, w);
    stage_w(wol_l, wl, t, w);
    stage_split32(ao + (size_t)r0 * H, ah, al, t);
    __syncthreads();

    const int arow = rw * 16 + c16;
    f32x4 acc[4];
    split_gemm4(ah, al, wh, wl, arow, g, c16, chw * 64, acc);

    float val[4][4], s1[4] = {0, 0, 0, 0}, s2[4] = {0, 0, 0, 0};
    #pragma unroll
    for (int sub = 0; sub < 4; ++sub) {
        int col = chw * 64 + sub * 16 + c16;
        float bias = ob[col];
        #pragma unroll
        for (int rr = 0; rr < 4; ++rr) {
            float vv = acc[sub][rr] + bias;
            val[sub][rr] = vv;
            s1[rr] += vv;
            s2[rr] += vv * vv;
        }
    }
    #pragma unroll
    for (int rr = 0; rr < 4; ++rr) {
        #pragma unroll
        for (int off = 1; off < 16; off <<= 1) {
            s1[rr] += __shfl_xor(s1[rr], off);
            s2[rr] += __shfl_xor(s2[rr], off);
        }
    }
    if (c16 == 0) {
        #pragma unroll
        for (int rr = 0; rr < 4; ++rr) {
            red1[chw][rw * 16 + g * 4 + rr] = s1[rr];
            red2[chw][rw * 16 + g * 4 + rr] = s2[rr];
        }
    }
    __syncthreads();   // red ready; all ah/al/wh/wl reads complete
    #pragma unroll
    for (int rr = 0; rr < 4; ++rr) {
        int rl = rw * 16 + g * 4 + rr;
        float t1 = red1[0][rl] + red1[1][rl];
        float t2 = red2[0][rl] + red2[1][rl];
        float mu = t1 * (1.0f / H);
        float var = t2 * (1.0f / H) - mu * mu;
        float rsn = rsqrtf(var + EPS);
        #pragma unroll
        for (int sub = 0; sub < 4; ++sub) {
            int col = chw * 64 + sub * 16 + c16;
            float y = (val[sub][rr] - mu) * rsn * lng[col] + lnb[col];
            float hn = fmaxf(y, 0.0f) + h[(size_t)(r0 + rl) * H + col];
            unsigned short hi = f2bf(hn);
            ah[rl * 130 + col] = hi;
            al[rl * 130 + col] = f2bf(hn - bf2f(hi));
        }
    }
    stage_w(wfh, wh, t, w);
    stage_w(wfl, wl, t, w);
    __syncthreads();

    f32x4 fac[4];
    split_gemm4(ah, al, wh, wl, arow, g, c16, chw * 64, fac);
    #pragma unroll
    for (int sub = 0; sub < 4; ++sub) {
        int col = chw * 64 + sub * 16 + c16;
        float bias = fb[col];
        #pragma unroll
        for (int rr = 0; rr < 4; ++rr) {
            int row = r0 + rw * 16 + g * 4 + rr;
            out[(size_t)row * H + col] = fac[sub][rr] + bias;
        }
    }
}

extern "C" void kernel_launch(void* const* d_in, const int* in_sizes, int n_in,
                              void* d_out, int out_size, void* d_ws, size_t ws_size,
                              hipStream_t stream) {
    const float* x     = (const float*)d_in[0];
    const float* adj   = (const float*)d_in[1];
    const float* enc_w = (const float*)d_in[2];
    const float* enc_b = (const float*)d_in[3];
    const float* q_w   = (const float*)d_in[4];
    const float* q_b   = (const float*)d_in[5];
    const float* k_w   = (const float*)d_in[6];
    const float* k_b   = (const float*)d_in[7];
    const float* v_w   = (const float*)d_in[8];
    const float* v_b   = (const float*)d_in[9];
    const float* o_w   = (const float*)d_in[10];
    const float* o_b   = (const float*)d_in[11];
    const float* ln_g  = (const float*)d_in[12];
    const float* ln_b  = (const float*)d_in[13];
    const float* out_w = (const float*)d_in[14];
    const float* out_b = (const float*)d_in[15];

    const size_t BNH = (size_t)B * N * H;
    float* h  = (float*)d_ws;
    float* ao = h + BNH;
    unsigned short* h_bf = (unsigned short*)(ao + BNH);
    unsigned short* qb = h_bf + BNH;
    unsigned short* kb = qb + BNH;
    unsigned short* vT = kb + BNH;
    unsigned* mbits = (unsigned*)(vT + BNH);
    unsigned short* wqkv = (unsigned short*)(mbits + (size_t)B * N * N / 32);
    float* bqkv = (float*)(wqkv + (size_t)L * 3 * H * H);
    unsigned short* woh = (unsigned short*)(bqkv + L * 3 * H);
    unsigned short* wol = woh + (size_t)L * H * H;
    unsigned short* wfh = wol + (size_t)L * H * H;
    unsigned short* wfl = wfh + (size_t)H * H;

    front_kernel<<<NPACK + NPREP + NENC, 256, 0, stream>>>(
        adj, x, enc_w, enc_b, q_w, k_w, v_w, q_b, k_b, v_b, o_w, out_w,
        mbits, wqkv, bqkv, woh, wol, wfh, wfl, h, h_bf);

    // layer 0
    qkv_kernel<<<B * N / 32, 256, 0, stream>>>(h_bf, wqkv, bqkv, qb, kb, vT);
    attn_kernel<<<B * HEADS * (N / 64), 256, 0, stream>>>(qb, kb, vT, mbits, ao);
    oln_kernel<<<B * N / 32, 256, 0, stream>>>(
        ao, woh, wol, o_b, ln_g, ln_b, h, h_bf);
    // layer 1 (+ final fused)
    qkv_kernel<<<B * N / 32, 256, 0, stream>>>(
        h_bf, wqkv + (size_t)3 * H * H, bqkv + 3 * H, qb, kb, vT);
    attn_kernel<<<B * HEADS * (N / 64), 256, 0, stream>>>(qb, kb, vT, mbits, ao);
    olnfinal_kernel<<<B * N / 32, 256, 0, stream>>>(
        ao, woh + (size_t)H * H, wol + (size_t)H * H, o_b + H,
        ln_g + H, ln_b + H, h, wfh, wfl, out_b, (float*)d_out);
}

// Round 13
// 90.660 us; speedup vs baseline: 1.1011x; 1.0110x over previous
//
#include <hip/hip_runtime.h>

#define B 8
#define N 1024
#define D_IN 64
#define H 128
#define HEADS 4
#define HD 32
#define L 2
#define EPS 1e-5f
#define NEG_BIG -1e30f
// 1/sqrt(32) * log2(e): softmax computed in base-2 domain (exp2f)
#define QSCALE (0.17677669529663687f * 1.4426950408889634f)

typedef __attribute__((ext_vector_type(8))) short bf16x8;
typedef __attribute__((ext_vector_type(4))) float f32x4;

__device__ __forceinline__ unsigned short f2bf(float f) {
    unsigned u = __float_as_uint(f);
    u = u + 0x7fffu + ((u >> 16) & 1u);
    return (unsigned short)(u >> 16);
}
__device__ __forceinline__ float bf2f(unsigned short s) {
    return __uint_as_float(((unsigned)s) << 16);
}
__device__ __forceinline__ void gload_lds16(const void* g, void* l) {
    __builtin_amdgcn_global_load_lds(
        (const __attribute__((address_space(1))) unsigned int*)g,
        (__attribute__((address_space(3))) unsigned int*)l,
        16, 0, 0);
}

#define NPACK 1024           // B*N*N/32/256
#define NPREP 579            // (L*3*H*H + L*3*H + L*H*H + H*H)/256
#define NENC  256            // B*N/32

// ======== fused front: adj-pack | weight-prep | encoder (independent roles) ========
__global__ __launch_bounds__(256) void front_kernel(
    const float* __restrict__ adj, const float* __restrict__ x,
    const float* __restrict__ enc_w, const float* __restrict__ eb,
    const float* __restrict__ q_w, const float* __restrict__ k_w,
    const float* __restrict__ v_w, const float* __restrict__ q_b,
    const float* __restrict__ k_b, const float* __restrict__ v_b,
    const float* __restrict__ o_w, const float* __restrict__ out_w,
    unsigned* __restrict__ mb, unsigned short* __restrict__ wqkv,
    float* __restrict__ bqkv, unsigned short* __restrict__ woh,
    unsigned short* __restrict__ wol, unsigned short* __restrict__ wfh,
    unsigned short* __restrict__ wfl, float* __restrict__ h,
    unsigned short* __restrict__ h_bf) {
    __shared__ unsigned short wt[H * D_IN];    // 16 KB (enc role only)
    __shared__ unsigned short at[32 * D_IN];   // 4 KB
    const int blk = blockIdx.x;
    const int t = threadIdx.x;

    if (blk < NPACK) {                 // ---- adj -> bitmask ----
        int wd = blk * 256 + t;
        const float4* src = (const float4*)(adj + (size_t)wd * 32);
        unsigned m = 0;
        #pragma unroll
        for (int c = 0; c < 8; ++c) {
            float4 f = src[c];
            if (f.x != 0.0f) m |= 1u << (c * 4 + 0);
            if (f.y != 0.0f) m |= 1u << (c * 4 + 1);
            if (f.z != 0.0f) m |= 1u << (c * 4 + 2);
            if (f.w != 0.0f) m |= 1u << (c * 4 + 3);
        }
        mb[wd] = m;
        return;
    }
    if (blk < NPACK + NPREP) {         // ---- weight prep ----
        int id = (blk - NPACK) * 256 + t;
        const int WQ = L * 3 * H * H;
        const int BQ = L * 3 * H;
        const int WO = L * H * H;
        if (id < WQ) {
            int layer = id / (3 * H * H);
            int r = id % (3 * H * H);
            int mat = r / (H * H);
            int e = r % (H * H);
            const float* src = mat == 0 ? q_w : (mat == 1 ? k_w : v_w);
            float f = src[layer * H * H + e];
            if (mat == 0) f *= QSCALE;
            wqkv[id] = f2bf(f);
            return;
        }
        id -= WQ;
        if (id < BQ) {
            int layer = id / (3 * H);
            int r = id % (3 * H);
            int mat = r / H;
            int e = r % H;
            const float* src = mat == 0 ? q_b : (mat == 1 ? k_b : v_b);
            float f = src[layer * H + e];
            if (mat == 0) f *= QSCALE;
            bqkv[id] = f;
            return;
        }
        id -= BQ;
        if (id < WO) {
            float f = o_w[id];
            unsigned short hi = f2bf(f);
            woh[id] = hi;
            wol[id] = f2bf(f - bf2f(hi));
            return;
        }
        id -= WO;
        {
            float f = out_w[id];
            unsigned short hi = f2bf(f);
            wfh[id] = hi;
            wfl[id] = f2bf(f - bf2f(hi));
        }
        return;
    }
    // ---- encoder: h = relu(x @ enc_w.T + b), 32-row blocks, in-kernel bf16 convert ----
    const int r0 = (blk - NPACK - NPREP) * 32;
    const int w = t >> 6, lane = t & 63, g = lane >> 4, c16 = lane & 15;
    const int rw = w & 1, chw = w >> 1;

    // stage enc_w (128x64) fp32 -> bf16 LDS, chunk-swizzled (key row&7)
    #pragma unroll
    for (int i = 0; i < 8; ++i) {
        int idx4 = i * 256 + t;
        int row = idx4 >> 4, c4 = (idx4 & 15) * 4;
        float4 f = ((const float4*)enc_w)[idx4];
        int off = row * 64 + (((c4 >> 3) ^ (row & 7)) * 8) + (c4 & 7);
        wt[off] = f2bf(f.x); wt[off + 1] = f2bf(f.y);
        wt[off + 2] = f2bf(f.z); wt[off + 3] = f2bf(f.w);
    }
    // stage x rows r0..r0+31
    #pragma unroll
    for (int i = 0; i < 2; ++i) {
        int idx4 = i * 256 + t;
        int row = idx4 >> 4, c4 = (idx4 & 15) * 4;
        float4 f = ((const float4*)(x + (size_t)r0 * D_IN))[idx4];
        int off = row * 64 + (((c4 >> 3) ^ (row & 7)) * 8) + (c4 & 7);
        at[off] = f2bf(f.x); at[off + 1] = f2bf(f.y);
        at[off + 2] = f2bf(f.z); at[off + 3] = f2bf(f.w);
    }
    __syncthreads();

    const int arow = rw * 16 + c16;
    bf16x8 a0 = *(const bf16x8*)(at + arow * 64 + ((g ^ (arow & 7)) * 8));
    bf16x8 a1 = *(const bf16x8*)(at + arow * 64 + (((4 + g) ^ (arow & 7)) * 8));
    f32x4 acc[4];
    #pragma unroll
    for (int sub = 0; sub < 4; ++sub) {
        int bcol = chw * 64 + sub * 16 + c16;
        bf16x8 b0 = *(const bf16x8*)(wt + bcol * 64 + ((g ^ (bcol & 7)) * 8));
        bf16x8 b1 = *(const bf16x8*)(wt + bcol * 64 + (((4 + g) ^ (bcol & 7)) * 8));
        f32x4 z = {0.f, 0.f, 0.f, 0.f};
        z = __builtin_amdgcn_mfma_f32_16x16x32_bf16(a0, b0, z, 0, 0, 0);
        acc[sub] = __builtin_amdgcn_mfma_f32_16x16x32_bf16(a1, b1, z, 0, 0, 0);
    }
    #pragma unroll
    for (int sub = 0; sub < 4; ++sub) {
        int col = chw * 64 + sub * 16 + c16;
        float bias = eb[col];
        #pragma unroll
        for (int rr = 0; rr < 4; ++rr) {
            int row = r0 + rw * 16 + g * 4 + rr;
            float v = fmaxf(acc[sub][rr] + bias, 0.0f);
            h[(size_t)row * H + col] = v;
            h_bf[(size_t)row * H + col] = f2bf(v);
        }
    }
}

// ------- fused q/k/v MFMA, col-split (grid 256): block = 64 rows x 192 cols -------
__global__ __launch_bounds__(256) void qkv_kernel(
    const unsigned short* __restrict__ h_bf, const unsigned short* __restrict__ wqkv_l,
    const float* __restrict__ bqkv_l,
    unsigned short* __restrict__ q, unsigned short* __restrict__ k,
    unsigned short* __restrict__ vT) {
    __shared__ unsigned short wt[192 * 128];
    __shared__ unsigned short at[64 * 128];
    const int t = threadIdx.x;
    const int r0 = (blockIdx.x >> 1) * 64;
    const int ch = blockIdx.x & 1;
    const int w = t >> 6, lane = t & 63, g = lane >> 4, c16 = lane & 15;
    const unsigned short* wsrc = wqkv_l + (size_t)ch * 192 * 128;

    #pragma unroll
    for (int i = 0; i < 12; ++i) {
        int ci = i * 256 + t, row = ci >> 4, cr = ci & 15;
        gload_lds16(wsrc + (size_t)row * 128 + (cr ^ (row & 7)) * 8,
                    (char*)wt + (i * 4 + w) * 1024);
    }
    #pragma unroll
    for (int i = 0; i < 4; ++i) {
        int ci = i * 256 + t, row = ci >> 4, cr = ci & 15;
        gload_lds16(h_bf + (size_t)(r0 + row) * 128 + (cr ^ (row & 7)) * 8,
                    (char*)at + (i * 4 + w) * 1024);
    }
    __syncthreads();

    const int arow = w * 16 + c16;
    bf16x8 a[4];
    #pragma unroll
    for (int ks = 0; ks < 4; ++ks)
        a[ks] = *(const bf16x8*)(at + arow * 128 + (((ks * 4 + g) ^ (arow & 7)) * 8));

    f32x4 acc[12];
    #pragma unroll
    for (int sub = 0; sub < 12; ++sub) {
        int bcol = sub * 16 + c16;
        f32x4 z = {0.f, 0.f, 0.f, 0.f};
        #pragma unroll
        for (int ks = 0; ks < 4; ++ks) {
            bf16x8 bb = *(const bf16x8*)(wt + (size_t)bcol * 128 + (((ks * 4 + g) ^ (bcol & 7)) * 8));
            z = __builtin_amdgcn_mfma_f32_16x16x32_bf16(a[ks], bb, z, 0, 0, 0);
        }
        acc[sub] = z;
    }
    #pragma unroll
    for (int sub = 0; sub < 12; ++sub) {
        int gcol = ch * 192 + sub * 16 + c16;
        int mat = gcol >> 7;
        int colin = gcol & 127;
        float bias = bqkv_l[mat * H + colin];
        if (mat < 2) {
            unsigned short* dst = mat == 0 ? q : k;
            #pragma unroll
            for (int rr = 0; rr < 4; ++rr) {
                int row = r0 + w * 16 + g * 4 + rr;
                dst[(size_t)row * H + colin] = f2bf(acc[sub][rr] + bias);
            }
        } else {
            int hd = colin >> 5, d = colin & 31;
            int bb = r0 >> 10;
            int jbase = (r0 & (N - 1)) + w * 16 + g * 4;
            int pos = (jbase & ~63) + ((((jbase >> 3) & 7) ^ (d & 7)) << 3) + (jbase & 7);
            float v0 = acc[sub][0] + bias, v1 = acc[sub][1] + bias;
            float v2 = acc[sub][2] + bias, v3 = acc[sub][3] + bias;
            unsigned lo, hi;
            asm("v_cvt_pk_bf16_f32 %0, %1, %2" : "=v"(lo) : "v"(v0), "v"(v1));
            asm("v_cvt_pk_bf16_f32 %0, %1, %2" : "=v"(hi) : "v"(v2), "v"(v3));
            uint2 pk2; pk2.x = lo; pk2.y = hi;
            *(uint2*)(vT + ((size_t)(bb * HEADS + hd) * HD + d) * N + pos) = pk2;
        }
    }
}

// ---------------- swapped-operand MFMA flash attention, KVBLK=128, exp2 domain ----------------
// XCD-aware block swizzle: all 16 i-tiles of one (b,head) group land on one XCD
// (dispatch d -> XCD d%8; we decode so grp%8 == d%8). K/V slice then L2-resident.
__global__ __launch_bounds__(256) void attn_kernel(
    const unsigned short* __restrict__ qg, const unsigned short* __restrict__ kg,
    const unsigned short* __restrict__ vTg, const unsigned* __restrict__ mb,
    float* __restrict__ ao) {
    __shared__ unsigned short qt[64 * 32];
    __shared__ unsigned short kt[2][128 * 32];
    __shared__ unsigned short vt[2][32 * 128];
    __shared__ unsigned short pl[4][16 * 136];

    const int bid = blockIdx.x;
    const int xcd = bid & 7;
    const int rem = bid >> 3;            // 0..63
    const int itile = rem & 15;
    const int grp = (rem >> 4) * 8 + xcd; // 0..31 = b*HEADS + head
    const int head = grp & 3;
    const int b = grp >> 2;
    const int i0 = itile * 64;
    const int bh = b * HEADS + head;

    const int t = threadIdx.x;
    const int w = t >> 6;
    const int lane = t & 63;
    const int g = lane >> 4;
    const int c16 = lane & 15;

    const int srow = t >> 2;
    const int sch = (t & 3) ^ ((t >> 2) & 3);

    gload_lds16(qg + ((size_t)(b * N + i0 + srow)) * H + head * HD + sch * 8,
                (char*)qt + w * 1024);
    #pragma unroll
    for (int i = 0; i < 2; ++i)
        gload_lds16(kg + ((size_t)(b * N + i * 64 + srow)) * H + head * HD + sch * 8,
                    (char*)kt[0] + i * 4096 + w * 1024);
    #pragma unroll
    for (int i = 0; i < 2; ++i) {
        int d = i * 16 + (t >> 4), c = t & 15;
        gload_lds16(vTg + ((size_t)bh * HD + d) * N + c * 8,
                    (char*)vt[0] + i * 4096 + w * 1024);
    }
    const unsigned* mrow = mb + (size_t)(b * N + i0 + w * 16 + c16) * (N / 32);
    uint4 am = *(const uint4*)mrow;

    __syncthreads();

    const int swq = c16 & 3;
    const bf16x8 qfrag = *(const bf16x8*)(qt + (w * 16 + c16) * 32 + ((g ^ swq) * 8));

    f32x4 oacc[2];
    oacc[0] = (f32x4){0.f, 0.f, 0.f, 0.f};
    oacc[1] = (f32x4){0.f, 0.f, 0.f, 0.f};
    float mrun = NEG_BIG, lrun = 0.0f;

    for (int jt = 0; jt < 8; ++jt) {
        const int cur = jt & 1;
        uint4 amn;
        if (jt < 7) {
            const int j0n = (jt + 1) * 128;
            #pragma unroll
            for (int i = 0; i < 2; ++i)
                gload_lds16(kg + ((size_t)(b * N + j0n + i * 64 + srow)) * H + head * HD + sch * 8,
                            (char*)kt[cur ^ 1] + i * 4096 + w * 1024);
            #pragma unroll
            for (int i = 0; i < 2; ++i) {
                int d = i * 16 + (t >> 4), c = t & 15;
                gload_lds16(vTg + ((size_t)bh * HD + d) * N + j0n + c * 8,
                            (char*)vt[cur ^ 1] + i * 4096 + w * 1024);
            }
            amn = *(const uint4*)(mrow + (jt + 1) * 4);
        }
        // ---- S^T (base-2 logits): 8 MFMAs ----
        f32x4 sacc[8];
        __builtin_amdgcn_s_setprio(1);
        #pragma unroll
        for (int jsub = 0; jsub < 8; ++jsub) {
            bf16x8 kfrag = *(const bf16x8*)(kt[cur] + (jsub * 16 + c16) * 32 + ((g ^ swq) * 8));
            f32x4 z = {0.f, 0.f, 0.f, 0.f};
            sacc[jsub] = __builtin_amdgcn_mfma_f32_16x16x32_bf16(kfrag, qfrag, z, 0, 0, 0);
        }
        __builtin_amdgcn_s_setprio(0);
        // ---- mask + per-lane online softmax ----
        float mx = NEG_BIG;
        #pragma unroll
        for (int jsub = 0; jsub < 8; ++jsub) {
            int wsel = jsub >> 1;
            unsigned mw = wsel == 0 ? am.x : wsel == 1 ? am.y : wsel == 2 ? am.z : am.w;
            #pragma unroll
            for (int r = 0; r < 4; ++r) {
                bool alive = (mw >> ((jsub & 1) * 16 + g * 4 + r)) & 1u;
                float s = alive ? sacc[jsub][r] : NEG_BIG;
                sacc[jsub][r] = s;
                mx = fmaxf(mx, s);
            }
        }
        mx = fmaxf(mx, __shfl_xor(mx, 16));
        mx = fmaxf(mx, __shfl_xor(mx, 32));
        float mnew = fmaxf(mrun, mx);
        float sf = exp2f(mrun - mnew);
        mrun = mnew;
        float rs = 0.0f;
        #pragma unroll
        for (int jsub = 0; jsub < 8; ++jsub)
            #pragma unroll
            for (int r = 0; r < 4; ++r) {
                float pv = exp2f(sacc[jsub][r] - mnew);   // masked -> underflow 0
                sacc[jsub][r] = pv;
                rs += pv;
            }
        rs += __shfl_xor(rs, 16);
        rs += __shfl_xor(rs, 32);
        lrun = lrun * sf + rs;
        // ---- pack P -> per-wave LDS ----
        #pragma unroll
        for (int jsub = 0; jsub < 8; ++jsub) {
            unsigned lo, hi;
            asm("v_cvt_pk_bf16_f32 %0, %1, %2" : "=v"(lo) : "v"(sacc[jsub][0]), "v"(sacc[jsub][1]));
            asm("v_cvt_pk_bf16_f32 %0, %1, %2" : "=v"(hi) : "v"(sacc[jsub][2]), "v"(sacc[jsub][3]));
            uint2 pk2; pk2.x = lo; pk2.y = hi;
            *(uint2*)(&pl[w][c16 * 136 + jsub * 16 + g * 4]) = pk2;
        }
        #pragma unroll
        for (int dsub = 0; dsub < 2; ++dsub)
            #pragma unroll
            for (int r = 0; r < 4; ++r)
                oacc[dsub][r] *= sf;
        asm volatile("s_waitcnt lgkmcnt(0)" ::: "memory");
        // ---- O^T += V^T P ----
        __builtin_amdgcn_s_setprio(1);
        #pragma unroll
        for (int ks = 0; ks < 4; ++ks) {
            bf16x8 pa = *(const bf16x8*)(&pl[w][c16 * 136 + ks * 32 + g * 8]);
            #pragma unroll
            for (int dsub = 0; dsub < 2; ++dsub) {
                int cj = ks * 4 + g;
                bf16x8 va = *(const bf16x8*)(vt[cur] + (dsub * 16 + c16) * 128 +
                                             (cj >> 3) * 64 + (((cj & 7) ^ (c16 & 7)) * 8));
                oacc[dsub] = __builtin_amdgcn_mfma_f32_16x16x32_bf16(va, pa, oacc[dsub], 0, 0, 0);
            }
        }
        __builtin_amdgcn_s_setprio(0);
        if (jt < 7) {
            am = amn;
            __syncthreads();
        }
    }
    float inv = (lrun > 0.0f) ? (1.0f / lrun) : 0.0f;
    #pragma unroll
    for (int dsub = 0; dsub < 2; ++dsub) {
        float4 o;
        o.x = oacc[dsub][0] * inv; o.y = oacc[dsub][1] * inv;
        o.z = oacc[dsub][2] * inv; o.w = oacc[dsub][3] * inv;
        *(float4*)(ao + ((size_t)(b * N + i0 + w * 16 + c16)) * H +
                   head * HD + dsub * 16 + g * 4) = o;
    }
}

// ---- split fp32 32-row tile -> bf16 hi/lo LDS (stride 130) ----
__device__ __forceinline__ void stage_split32(
    const float* __restrict__ src, unsigned short* hi, unsigned short* lo, int t) {
    #pragma unroll
    for (int it = 0; it < 4; ++it) {
        int idx4 = it * 256 + t;
        int row = idx4 >> 5, c4 = (idx4 & 31) * 4;
        float4 f = ((const float4*)src)[idx4];
        unsigned short h0 = f2bf(f.x), h1 = f2bf(f.y), h2 = f2bf(f.z), h3 = f2bf(f.w);
        unsigned short l0 = f2bf(f.x - bf2f(h0)), l1 = f2bf(f.y - bf2f(h1));
        unsigned short l2 = f2bf(f.z - bf2f(h2)), l3 = f2bf(f.w - bf2f(h3));
        *(unsigned*)(hi + row * 130 + c4)     = (unsigned)h0 | ((unsigned)h1 << 16);
        *(unsigned*)(hi + row * 130 + c4 + 2) = (unsigned)h2 | ((unsigned)h3 << 16);
        *(unsigned*)(lo + row * 130 + c4)     = (unsigned)l0 | ((unsigned)l1 << 16);
        *(unsigned*)(lo + row * 130 + c4 + 2) = (unsigned)l2 | ((unsigned)l3 << 16);
    }
}

// ---- 3-term split GEMM, 4 col-subtiles at offset bcol0 ----
__device__ __forceinline__ void split_gemm4(
    const unsigned short* ah, const unsigned short* al,
    const unsigned short* wh, const unsigned short* wl,
    int arow, int g, int c16, int bcol0, f32x4* acc) {
    bf16x8 ahf[4], alf[4];
    #pragma unroll
    for (int ks = 0; ks < 4; ++ks) {
        ahf[ks] = *(const bf16x8*)(ah + arow * 130 + ks * 32 + g * 8);
        alf[ks] = *(const bf16x8*)(al + arow * 130 + ks * 32 + g * 8);
    }
    #pragma unroll
    for (int sub = 0; sub < 4; ++sub) {
        int bcol = bcol0 + sub * 16 + c16;
        f32x4 z = {0.f, 0.f, 0.f, 0.f};
        #pragma unroll
        for (int ks = 0; ks < 4; ++ks) {
            bf16x8 bh = *(const bf16x8*)(wh + bcol * 128 + (((ks * 4 + g) ^ (bcol & 7)) * 8));
            bf16x8 bl = *(const bf16x8*)(wl + bcol * 128 + (((ks * 4 + g) ^ (bcol & 7)) * 8));
            z = __builtin_amdgcn_mfma_f32_16x16x32_bf16(ahf[ks], bh, z, 0, 0, 0);
            z = __builtin_amdgcn_mfma_f32_16x16x32_bf16(alf[ks], bh, z, 0, 0, 0);
            z = __builtin_amdgcn_mfma_f32_16x16x32_bf16(ahf[ks], bl, z, 0, 0, 0);
        }
        acc[sub] = z;
    }
}

__device__ __forceinline__ void stage_w(const unsigned short* __restrict__ src,
                                        unsigned short* dst, int t, int w) {
    #pragma unroll
    for (int i = 0; i < 8; ++i) {
        int ci = i * 256 + t, row = ci >> 4, cr = ci & 15;
        gload_lds16(src + (size_t)row * 128 + (cr ^ (row & 7)) * 8,
                    (char*)dst + (i * 4 + w) * 1024);
    }
}

// ------- layer-0: O-proj + LN + relu + residual, 32-row blocks (grid 256) -------
__global__ __launch_bounds__(256) void oln_kernel(
    const float* __restrict__ ao, const unsigned short* __restrict__ woh_l,
    const unsigned short* __restrict__ wol_l, const float* __restrict__ ob,
    const float* __restrict__ lng, const float* __restrict__ lnb,
    float* __restrict__ h, unsigned short* __restrict__ h_bf) {
    __shared__ unsigned short ah[32 * 130], al[32 * 130];
    __shared__ unsigned short wh[128 * 128], wl[128 * 128];
    __shared__ float red1[2][32], red2[2][32];
    const int t = threadIdx.x;
    const int r0 = blockIdx.x * 32;
    const int w = t >> 6, lane = t & 63, g = lane >> 4, c16 = lane & 15;
    const int rw = w & 1, chw = w >> 1;

    stage_w(woh_l, wh, t, w);
    stage_w(wol_l, wl, t, w);
    stage_split32(ao + (size_t)r0 * H, ah, al, t);
    __syncthreads();

    const int arow = rw * 16 + c16;
    f32x4 acc[4];
    split_gemm4(ah, al, wh, wl, arow, g, c16, chw * 64, acc);

    float val[4][4], s1[4] = {0, 0, 0, 0}, s2[4] = {0, 0, 0, 0};
    #pragma unroll
    for (int sub = 0; sub < 4; ++sub) {
        int col = chw * 64 + sub * 16 + c16;
        float bias = ob[col];
        #pragma unroll
        for (int rr = 0; rr < 4; ++rr) {
            float vv = acc[sub][rr] + bias;
            val[sub][rr] = vv;
            s1[rr] += vv;
            s2[rr] += vv * vv;
        }
    }
    #pragma unroll
    for (int rr = 0; rr < 4; ++rr) {
        #pragma unroll
        for (int off = 1; off < 16; off <<= 1) {
            s1[rr] += __shfl_xor(s1[rr], off);
            s2[rr] += __shfl_xor(s2[rr], off);
        }
    }
    if (c16 == 0) {
        #pragma unroll
        for (int rr = 0; rr < 4; ++rr) {
            red1[chw][rw * 16 + g * 4 + rr] = s1[rr];
            red2[chw][rw * 16 + g * 4 + rr] = s2[rr];
        }
    }
    __syncthreads();
    #pragma unroll
    for (int rr = 0; rr < 4; ++rr) {
        int rl = rw * 16 + g * 4 + rr;
        float t1 = red1[0][rl] + red1[1][rl];
        float t2 = red2[0][rl] + red2[1][rl];
        float mu = t1 * (1.0f / H);
        float var = t2 * (1.0f / H) - mu * mu;
        float rsn = rsqrtf(var + EPS);
        int row = r0 + rl;
        #pragma unroll
        for (int sub = 0; sub < 4; ++sub) {
            int col = chw * 64 + sub * 16 + c16;
            float y = (val[sub][rr] - mu) * rsn * lng[col] + lnb[col];
            float hn = fmaxf(y, 0.0f) + h[(size_t)row * H + col];
            h[(size_t)row * H + col] = hn;
            h_bf[(size_t)row * H + col] = f2bf(hn);
        }
    }
}

// ------- layer-1 fused: O-proj + LN + relu + residual + final proj, 32-row blocks -------
__global__ __launch_bounds__(256) void olnfinal_kernel(
    const float* __restrict__ ao, const unsigned short* __restrict__ woh_l,
    const unsigned short* __restrict__ wol_l, const float* __restrict__ ob,
    const float* __restrict__ lng, const float* __restrict__ lnb,
    const float* __restrict__ h, const unsigned short* __restrict__ wfh,
    const unsigned short* __restrict__ wfl, const float* __restrict__ fb,
    float* __restrict__ out) {
    __shared__ unsigned short ah[32 * 130], al[32 * 130];
    __shared__ unsigned short wh[128 * 128], wl[128 * 128];
    __shared__ float red1[2][32], red2[2][32];
    const int t = threadIdx.x;
    const int r0 = blockIdx.x * 32;
    const int w = t >> 6, lane = t & 63, g = lane >> 4, c16 = lane & 15;
    const int rw = w & 1, chw = w >> 1;

    stage_w(woh_l, wh, t, w);
    stage_w(wol_l, wl, t, w);
    stage_split32(ao + (size_t)r0 * H, ah, al, t);
    __syncthreads();

    const int arow = rw * 16 + c16;
    f32x4 acc[4];
    split_gemm4(ah, al, wh, wl, arow, g, c16, chw * 64, acc);

    float val[4][4], s1[4] = {0, 0, 0, 0}, s2[4] = {0, 0, 0, 0};
    #pragma unroll
    for (int sub = 0; sub < 4; ++sub) {
        int col = chw * 64 + sub * 16 + c16;
        float bias = ob[col];
        #pragma unroll
        for (int rr = 0; rr < 4; ++rr) {
            float vv = acc[sub][rr] + bias;
            val[sub][rr] = vv;
            s1[rr] += vv;
            s2[rr] += vv * vv;
        }
    }
    #pragma unroll
    for (int rr = 0; rr < 4; ++rr) {
        #pragma unroll
        for (int off = 1; off < 16; off <<= 1) {
            s1[rr] += __shfl_xor(s1[rr], off);
            s2[rr] += __shfl_xor(s2[rr], off);
        }
    }
    if (c16 == 0) {
        #pragma unroll
        for (int rr = 0; rr < 4; ++rr) {
            red1[chw][rw * 16 + g * 4 + rr] = s1[rr];
            red2[chw][rw * 16 + g * 4 + rr] = s2[rr];
        }
    }
    __syncthreads();   // red ready; all ah/al/wh/wl reads complete
    #pragma unroll
    for (int rr = 0; rr < 4; ++rr) {
        int rl = rw * 16 + g * 4 + rr;
        float t1 = red1[0][rl] + red1[1][rl];
        float t2 = red2[0][rl] + red2[1][rl];
        float mu = t1 * (1.0f / H);
        float var = t2 * (1.0f / H) - mu * mu;
        float rsn = rsqrtf(var + EPS);
        #pragma unroll
        for (int sub = 0; sub < 4; ++sub) {
            int col = chw * 64 + sub * 16 + c16;
            float y = (val[sub][rr] - mu) * rsn * lng[col] + lnb[col];
            float hn = fmaxf(y, 0.0f) + h[(size_t)(r0 + rl) * H + col];
            unsigned short hi = f2bf(hn);
            ah[rl * 130 + col] = hi;
            al[rl * 130 + col] = f2bf(hn - bf2f(hi));
        }
    }
    stage_w(wfh, wh, t, w);
    stage_w(wfl, wl, t, w);
    __syncthreads();

    f32x4 fac[4];
    split_gemm4(ah, al, wh, wl, arow, g, c16, chw * 64, fac);
    #pragma unroll
    for (int sub = 0; sub < 4; ++sub) {
        int col = chw * 64 + sub * 16 + c16;
        float bias = fb[col];
        #pragma unroll
        for (int rr = 0; rr < 4; ++rr) {
            int row = r0 + rw * 16 + g * 4 + rr;
            out[(size_t)row * H + col] = fac[sub][rr] + bias;
        }
    }
}

extern "C" void kernel_launch(void* const* d_in, const int* in_sizes, int n_in,
                              void* d_out, int out_size, void* d_ws, size_t ws_size,
                              hipStream_t stream) {
    const float* x     = (const float*)d_in[0];
    const float* adj   = (const float*)d_in[1];
    const float* enc_w = (const float*)d_in[2];
    const float* enc_b = (const float*)d_in[3];
    const float* q_w   = (const float*)d_in[4];
    const float* q_b   = (const float*)d_in[5];
    const float* k_w   = (const float*)d_in[6];
    const float* k_b   = (const float*)d_in[7];
    const float* v_w   = (const float*)d_in[8];
    const float* v_b   = (const float*)d_in[9];
    const float* o_w   = (const float*)d_in[10];
    const float* o_b   = (const float*)d_in[11];
    const float* ln_g  = (const float*)d_in[12];
    const float* ln_b  = (const float*)d_in[13];
    const float* out_w = (const float*)d_in[14];
    const float* out_b = (const float*)d_in[15];

    const size_t BNH = (size_t)B * N * H;
    float* h  = (float*)d_ws;
    float* ao = h + BNH;
    unsigned short* h_bf = (unsigned short*)(ao + BNH);
    unsigned short* qb = h_bf + BNH;
    unsigned short* kb = qb + BNH;
    unsigned short* vT = kb + BNH;
    unsigned* mbits = (unsigned*)(vT + BNH);
    unsigned short* wqkv = (unsigned short*)(mbits + (size_t)B * N * N / 32);
    float* bqkv = (float*)(wqkv + (size_t)L * 3 * H * H);
    unsigned short* woh = (unsigned short*)(bqkv + L * 3 * H);
    unsigned short* wol = woh + (size_t)L * H * H;
    unsigned short* wfh = wol + (size_t)L * H * H;
    unsigned short* wfl = wfh + (size_t)H * H;

    front_kernel<<<NPACK + NPREP + NENC, 256, 0, stream>>>(
        adj, x, enc_w, enc_b, q_w, k_w, v_w, q_b, k_b, v_b, o_w, out_w,
        mbits, wqkv, bqkv, woh, wol, wfh, wfl, h, h_bf);

    // layer 0
    qkv_kernel<<<B * N / 32, 256, 0, stream>>>(h_bf, wqkv, bqkv, qb, kb, vT);
    attn_kernel<<<B * HEADS * (N / 64), 256, 0, stream>>>(qb, kb, vT, mbits, ao);
    oln_kernel<<<B * N / 32, 256, 0, stream>>>(
        ao, woh, wol, o_b, ln_g, ln_b, h, h_bf);
    // layer 1 (+ final fused)
    qkv_kernel<<<B * N / 32, 256, 0, stream>>>(
        h_bf, wqkv + (size_t)3 * H * H, bqkv + 3 * H, qb, kb, vT);
    attn_kernel<<<B * HEADS * (N / 64), 256, 0, stream>>>(qb, kb, vT, mbits, ao);
    olnfinal_kernel<<<B * N / 32, 256, 0, stream>>>(
        ao, woh + (size_t)H * H, wol + (size_t)H * H, o_b + H,
        ln_g + H, ln_b + H, h, wfh, wfl, out_b, (float*)d_out);
}

// Round 14
// 89.067 us; speedup vs baseline: 1.1208x; 1.0179x over previous
//
#include <hip/hip_runtime.h>

#define B 8
#define N 1024
#define D_IN 64
#define H 128
#define HEADS 4
#define HD 32
#define L 2
#define EPS 1e-5f
#define NEG_BIG -1e30f
// 1/sqrt(32) * log2(e): softmax computed in base-2 domain (exp2f)
#define QSCALE (0.17677669529663687f * 1.4426950408889634f)

typedef __attribute__((ext_vector_type(8))) short bf16x8;
typedef __attribute__((ext_vector_type(4))) float f32x4;

__device__ __forceinline__ unsigned short f2bf(float f) {
    unsigned u = __float_as_uint(f);
    u = u + 0x7fffu + ((u >> 16) & 1u);
    return (unsigned short)(u >> 16);
}
__device__ __forceinline__ float bf2f(unsigned short s) {
    return __uint_as_float(((unsigned)s) << 16);
}
__device__ __forceinline__ void gload_lds16(const void* g, void* l) {
    __builtin_amdgcn_global_load_lds(
        (const __attribute__((address_space(1))) unsigned int*)g,
        (__attribute__((address_space(3))) unsigned int*)l,
        16, 0, 0);
}

#define NPACK 1024           // B*N*N/32/256
#define NPREP 579            // (L*3*H*H + L*3*H + L*H*H + H*H)/256
#define NENC  256            // B*N/32

// ======== fused front: adj-pack | weight-prep | encoder (independent roles) ========
__global__ __launch_bounds__(256) void front_kernel(
    const float* __restrict__ adj, const float* __restrict__ x,
    const float* __restrict__ enc_w, const float* __restrict__ eb,
    const float* __restrict__ q_w, const float* __restrict__ k_w,
    const float* __restrict__ v_w, const float* __restrict__ q_b,
    const float* __restrict__ k_b, const float* __restrict__ v_b,
    const float* __restrict__ o_w, const float* __restrict__ out_w,
    unsigned* __restrict__ mb, unsigned short* __restrict__ wqkv,
    float* __restrict__ bqkv, unsigned short* __restrict__ woh,
    unsigned short* __restrict__ wol, unsigned short* __restrict__ wfh,
    unsigned short* __restrict__ wfl, float* __restrict__ h,
    unsigned short* __restrict__ h_bf) {
    __shared__ unsigned short wt[H * D_IN];    // 16 KB (enc role only)
    __shared__ unsigned short at[32 * D_IN];   // 4 KB
    const int blk = blockIdx.x;
    const int t = threadIdx.x;

    if (blk < NPACK) {                 // ---- adj -> bitmask ----
        int wd = blk * 256 + t;
        const float4* src = (const float4*)(adj + (size_t)wd * 32);
        unsigned m = 0;
        #pragma unroll
        for (int c = 0; c < 8; ++c) {
            float4 f = src[c];
            if (f.x != 0.0f) m |= 1u << (c * 4 + 0);
            if (f.y != 0.0f) m |= 1u << (c * 4 + 1);
            if (f.z != 0.0f) m |= 1u << (c * 4 + 2);
            if (f.w != 0.0f) m |= 1u << (c * 4 + 3);
        }
        mb[wd] = m;
        return;
    }
    if (blk < NPACK + NPREP) {         // ---- weight prep ----
        int id = (blk - NPACK) * 256 + t;
        const int WQ = L * 3 * H * H;
        const int BQ = L * 3 * H;
        const int WO = L * H * H;
        if (id < WQ) {
            int layer = id / (3 * H * H);
            int r = id % (3 * H * H);
            int mat = r / (H * H);
            int e = r % (H * H);
            const float* src = mat == 0 ? q_w : (mat == 1 ? k_w : v_w);
            float f = src[layer * H * H + e];
            if (mat == 0) f *= QSCALE;
            wqkv[id] = f2bf(f);
            return;
        }
        id -= WQ;
        if (id < BQ) {
            int layer = id / (3 * H);
            int r = id % (3 * H);
            int mat = r / H;
            int e = r % H;
            const float* src = mat == 0 ? q_b : (mat == 1 ? k_b : v_b);
            float f = src[layer * H + e];
            if (mat == 0) f *= QSCALE;
            bqkv[id] = f;
            return;
        }
        id -= BQ;
        if (id < WO) {
            float f = o_w[id];
            unsigned short hi = f2bf(f);
            woh[id] = hi;
            wol[id] = f2bf(f - bf2f(hi));
            return;
        }
        id -= WO;
        {
            float f = out_w[id];
            unsigned short hi = f2bf(f);
            wfh[id] = hi;
            wfl[id] = f2bf(f - bf2f(hi));
        }
        return;
    }
    // ---- encoder: h = relu(x @ enc_w.T + b), 32-row blocks, in-kernel bf16 convert ----
    const int r0 = (blk - NPACK - NPREP) * 32;
    const int w = t >> 6, lane = t & 63, g = lane >> 4, c16 = lane & 15;
    const int rw = w & 1, chw = w >> 1;

    #pragma unroll
    for (int i = 0; i < 8; ++i) {
        int idx4 = i * 256 + t;
        int row = idx4 >> 4, c4 = (idx4 & 15) * 4;
        float4 f = ((const float4*)enc_w)[idx4];
        int off = row * 64 + (((c4 >> 3) ^ (row & 7)) * 8) + (c4 & 7);
        wt[off] = f2bf(f.x); wt[off + 1] = f2bf(f.y);
        wt[off + 2] = f2bf(f.z); wt[off + 3] = f2bf(f.w);
    }
    #pragma unroll
    for (int i = 0; i < 2; ++i) {
        int idx4 = i * 256 + t;
        int row = idx4 >> 4, c4 = (idx4 & 15) * 4;
        float4 f = ((const float4*)(x + (size_t)r0 * D_IN))[idx4];
        int off = row * 64 + (((c4 >> 3) ^ (row & 7)) * 8) + (c4 & 7);
        at[off] = f2bf(f.x); at[off + 1] = f2bf(f.y);
        at[off + 2] = f2bf(f.z); at[off + 3] = f2bf(f.w);
    }
    __syncthreads();

    const int arow = rw * 16 + c16;
    bf16x8 a0 = *(const bf16x8*)(at + arow * 64 + ((g ^ (arow & 7)) * 8));
    bf16x8 a1 = *(const bf16x8*)(at + arow * 64 + (((4 + g) ^ (arow & 7)) * 8));
    f32x4 acc[4];
    #pragma unroll
    for (int sub = 0; sub < 4; ++sub) {
        int bcol = chw * 64 + sub * 16 + c16;
        bf16x8 b0 = *(const bf16x8*)(wt + bcol * 64 + ((g ^ (bcol & 7)) * 8));
        bf16x8 b1 = *(const bf16x8*)(wt + bcol * 64 + (((4 + g) ^ (bcol & 7)) * 8));
        f32x4 z = {0.f, 0.f, 0.f, 0.f};
        z = __builtin_amdgcn_mfma_f32_16x16x32_bf16(a0, b0, z, 0, 0, 0);
        acc[sub] = __builtin_amdgcn_mfma_f32_16x16x32_bf16(a1, b1, z, 0, 0, 0);
    }
    #pragma unroll
    for (int sub = 0; sub < 4; ++sub) {
        int col = chw * 64 + sub * 16 + c16;
        float bias = eb[col];
        #pragma unroll
        for (int rr = 0; rr < 4; ++rr) {
            int row = r0 + rw * 16 + g * 4 + rr;
            float v = fmaxf(acc[sub][rr] + bias, 0.0f);
            h[(size_t)row * H + col] = v;
            h_bf[(size_t)row * H + col] = f2bf(v);
        }
    }
}

// ------- fused q/k/v MFMA, col-split (grid 256): block = 64 rows x 192 cols -------
__global__ __launch_bounds__(256) void qkv_kernel(
    const unsigned short* __restrict__ h_bf, const unsigned short* __restrict__ wqkv_l,
    const float* __restrict__ bqkv_l,
    unsigned short* __restrict__ q, unsigned short* __restrict__ k,
    unsigned short* __restrict__ vT) {
    __shared__ unsigned short wt[192 * 128];
    __shared__ unsigned short at[64 * 128];
    const int t = threadIdx.x;
    const int r0 = (blockIdx.x >> 1) * 64;
    const int ch = blockIdx.x & 1;
    const int w = t >> 6, lane = t & 63, g = lane >> 4, c16 = lane & 15;
    const unsigned short* wsrc = wqkv_l + (size_t)ch * 192 * 128;

    #pragma unroll
    for (int i = 0; i < 12; ++i) {
        int ci = i * 256 + t, row = ci >> 4, cr = ci & 15;
        gload_lds16(wsrc + (size_t)row * 128 + (cr ^ (row & 7)) * 8,
                    (char*)wt + (i * 4 + w) * 1024);
    }
    #pragma unroll
    for (int i = 0; i < 4; ++i) {
        int ci = i * 256 + t, row = ci >> 4, cr = ci & 15;
        gload_lds16(h_bf + (size_t)(r0 + row) * 128 + (cr ^ (row & 7)) * 8,
                    (char*)at + (i * 4 + w) * 1024);
    }
    __syncthreads();

    const int arow = w * 16 + c16;
    bf16x8 a[4];
    #pragma unroll
    for (int ks = 0; ks < 4; ++ks)
        a[ks] = *(const bf16x8*)(at + arow * 128 + (((ks * 4 + g) ^ (arow & 7)) * 8));

    f32x4 acc[12];
    #pragma unroll
    for (int sub = 0; sub < 12; ++sub) {
        int bcol = sub * 16 + c16;
        f32x4 z = {0.f, 0.f, 0.f, 0.f};
        #pragma unroll
        for (int ks = 0; ks < 4; ++ks) {
            bf16x8 bb = *(const bf16x8*)(wt + (size_t)bcol * 128 + (((ks * 4 + g) ^ (bcol & 7)) * 8));
            z = __builtin_amdgcn_mfma_f32_16x16x32_bf16(a[ks], bb, z, 0, 0, 0);
        }
        acc[sub] = z;
    }
    #pragma unroll
    for (int sub = 0; sub < 12; ++sub) {
        int gcol = ch * 192 + sub * 16 + c16;
        int mat = gcol >> 7;
        int colin = gcol & 127;
        float bias = bqkv_l[mat * H + colin];
        if (mat < 2) {
            unsigned short* dst = mat == 0 ? q : k;
            #pragma unroll
            for (int rr = 0; rr < 4; ++rr) {
                int row = r0 + w * 16 + g * 4 + rr;
                dst[(size_t)row * H + colin] = f2bf(acc[sub][rr] + bias);
            }
        } else {
            int hd = colin >> 5, d = colin & 31;
            int bb = r0 >> 10;
            int jbase = (r0 & (N - 1)) + w * 16 + g * 4;
            int pos = (jbase & ~63) + ((((jbase >> 3) & 7) ^ (d & 7)) << 3) + (jbase & 7);
            float v0 = acc[sub][0] + bias, v1 = acc[sub][1] + bias;
            float v2 = acc[sub][2] + bias, v3 = acc[sub][3] + bias;
            unsigned lo, hi;
            asm("v_cvt_pk_bf16_f32 %0, %1, %2" : "=v"(lo) : "v"(v0), "v"(v1));
            asm("v_cvt_pk_bf16_f32 %0, %1, %2" : "=v"(hi) : "v"(v2), "v"(v3));
            uint2 pk2; pk2.x = lo; pk2.y = hi;
            *(uint2*)(vT + ((size_t)(bb * HEADS + hd) * HD + d) * N + pos) = pk2;
        }
    }
}

// ---- swapped-operand MFMA flash attention, KVBLK=128, 3-buffer 2-deep prefetch ----
// Counted vmcnt (T3/T4): raw s_barrier + vmcnt(4) -> next-tile loads stay in flight;
// the tile read after each barrier was issued TWO compute phases earlier.
__global__ __launch_bounds__(256) void attn_kernel(
    const unsigned short* __restrict__ qg, const unsigned short* __restrict__ kg,
    const unsigned short* __restrict__ vTg, const unsigned* __restrict__ mb,
    float* __restrict__ ao) {
    __shared__ unsigned short qt[64 * 32];          // 4 KB
    __shared__ unsigned short kt[3][128 * 32];      // 24 KB
    __shared__ unsigned short vt[3][32 * 128];      // 24 KB
    __shared__ unsigned short pl[4][16 * 136];      // 17 KB

    const int bid = blockIdx.x;
    const int xcd = bid & 7;
    const int rem = bid >> 3;
    const int itile = rem & 15;
    const int grp = (rem >> 4) * 8 + xcd;
    const int head = grp & 3;
    const int b = grp >> 2;
    const int i0 = itile * 64;
    const int bh = b * HEADS + head;

    const int t = threadIdx.x;
    const int w = t >> 6;
    const int lane = t & 63;
    const int g = lane >> 4;
    const int c16 = lane & 15;

    const int srow = t >> 2;
    const int sch = (t & 3) ^ ((t >> 2) & 3);

    // ---- masks first (oldest vmcnt ops; statically indexed, full-unrolled uses) ----
    const unsigned* mrow = mb + (size_t)(b * N + i0 + w * 16 + c16) * (N / 32);
    uint4 am[8];
    #pragma unroll
    for (int jt = 0; jt < 8; ++jt) am[jt] = *(const uint4*)(mrow + jt * 4);

    // ---- Q + tiles 0,1 ----
    gload_lds16(qg + ((size_t)(b * N + i0 + srow)) * H + head * HD + sch * 8,
                (char*)qt + w * 1024);
    #pragma unroll
    for (int tt = 0; tt < 2; ++tt) {
        const int j0 = tt * 128;
        #pragma unroll
        for (int i = 0; i < 2; ++i)
            gload_lds16(kg + ((size_t)(b * N + j0 + i * 64 + srow)) * H + head * HD + sch * 8,
                        (char*)kt[tt] + i * 4096 + w * 1024);
        #pragma unroll
        for (int i = 0; i < 2; ++i) {
            int d = i * 16 + (t >> 4), c = t & 15;
            gload_lds16(vTg + ((size_t)bh * HD + d) * N + j0 + c * 8,
                        (char*)vt[tt] + i * 4096 + w * 1024);
        }
    }
    // wait: everything except tile1's 4 loads -> Q + tile0 (and masks) landed
    asm volatile("s_waitcnt vmcnt(4)" ::: "memory");
    __builtin_amdgcn_s_barrier();

    const int swq = c16 & 3;
    const bf16x8 qfrag = *(const bf16x8*)(qt + (w * 16 + c16) * 32 + ((g ^ swq) * 8));

    f32x4 oacc[2];
    oacc[0] = (f32x4){0.f, 0.f, 0.f, 0.f};
    oacc[1] = (f32x4){0.f, 0.f, 0.f, 0.f};
    float mrun = NEG_BIG, lrun = 0.0f;

    #pragma unroll
    for (int jt = 0; jt < 8; ++jt) {
        const int cur = jt % 3;
        // ---- issue tile jt+2 into buf (jt+2)%3 == (jt-1)%3 (all waves done reading it) ----
        if (jt < 6) {
            const int nb = (jt + 2) % 3;
            const int j0n = (jt + 2) * 128;
            #pragma unroll
            for (int i = 0; i < 2; ++i)
                gload_lds16(kg + ((size_t)(b * N + j0n + i * 64 + srow)) * H + head * HD + sch * 8,
                            (char*)kt[nb] + i * 4096 + w * 1024);
            #pragma unroll
            for (int i = 0; i < 2; ++i) {
                int d = i * 16 + (t >> 4), c = t & 15;
                gload_lds16(vTg + ((size_t)bh * HD + d) * N + j0n + c * 8,
                            (char*)vt[nb] + i * 4096 + w * 1024);
            }
        }
        // ---- S^T (base-2 logits): 8 MFMAs ----
        f32x4 sacc[8];
        __builtin_amdgcn_s_setprio(1);
        #pragma unroll
        for (int jsub = 0; jsub < 8; ++jsub) {
            bf16x8 kfrag = *(const bf16x8*)(kt[cur] + (jsub * 16 + c16) * 32 + ((g ^ swq) * 8));
            f32x4 z = {0.f, 0.f, 0.f, 0.f};
            sacc[jsub] = __builtin_amdgcn_mfma_f32_16x16x32_bf16(kfrag, qfrag, z, 0, 0, 0);
        }
        __builtin_amdgcn_s_setprio(0);
        // ---- mask + per-lane online softmax ----
        float mx = NEG_BIG;
        #pragma unroll
        for (int jsub = 0; jsub < 8; ++jsub) {
            int wsel = jsub >> 1;
            unsigned mw = wsel == 0 ? am[jt].x : wsel == 1 ? am[jt].y
                        : wsel == 2 ? am[jt].z : am[jt].w;
            #pragma unroll
            for (int r = 0; r < 4; ++r) {
                bool alive = (mw >> ((jsub & 1) * 16 + g * 4 + r)) & 1u;
                float s = alive ? sacc[jsub][r] : NEG_BIG;
                sacc[jsub][r] = s;
                mx = fmaxf(mx, s);
            }
        }
        mx = fmaxf(mx, __shfl_xor(mx, 16));
        mx = fmaxf(mx, __shfl_xor(mx, 32));
        float mnew = fmaxf(mrun, mx);
        float sf = exp2f(mrun - mnew);
        mrun = mnew;
        float rs = 0.0f;
        #pragma unroll
        for (int jsub = 0; jsub < 8; ++jsub)
            #pragma unroll
            for (int r = 0; r < 4; ++r) {
                float pv = exp2f(sacc[jsub][r] - mnew);   // masked -> underflow 0
                sacc[jsub][r] = pv;
                rs += pv;
            }
        rs += __shfl_xor(rs, 16);
        rs += __shfl_xor(rs, 32);
        lrun = lrun * sf + rs;
        // ---- pack P -> per-wave LDS ----
        #pragma unroll
        for (int jsub = 0; jsub < 8; ++jsub) {
            unsigned lo, hi;
            asm("v_cvt_pk_bf16_f32 %0, %1, %2" : "=v"(lo) : "v"(sacc[jsub][0]), "v"(sacc[jsub][1]));
            asm("v_cvt_pk_bf16_f32 %0, %1, %2" : "=v"(hi) : "v"(sacc[jsub][2]), "v"(sacc[jsub][3]));
            uint2 pk2; pk2.x = lo; pk2.y = hi;
            *(uint2*)(&pl[w][c16 * 136 + jsub * 16 + g * 4]) = pk2;
        }
        #pragma unroll
        for (int dsub = 0; dsub < 2; ++dsub)
            #pragma unroll
            for (int r = 0; r < 4; ++r)
                oacc[dsub][r] *= sf;
        asm volatile("s_waitcnt lgkmcnt(0)" ::: "memory");
        // ---- O^T += V^T P ----
        __builtin_amdgcn_s_setprio(1);
        #pragma unroll
        for (int ks = 0; ks < 4; ++ks) {
            bf16x8 pa = *(const bf16x8*)(&pl[w][c16 * 136 + ks * 32 + g * 8]);
            #pragma unroll
            for (int dsub = 0; dsub < 2; ++dsub) {
                int cj = ks * 4 + g;
                bf16x8 va = *(const bf16x8*)(vt[cur] + (dsub * 16 + c16) * 128 +
                                             (cj >> 3) * 64 + (((cj & 7) ^ (c16 & 7)) * 8));
                oacc[dsub] = __builtin_amdgcn_mfma_f32_16x16x32_bf16(va, pa, oacc[dsub], 0, 0, 0);
            }
        }
        __builtin_amdgcn_s_setprio(0);
        // ---- tile boundary: counted wait (tile jt+1 resident; jt+2 stays in flight) ----
        if (jt < 7) {
            if (jt < 6) asm volatile("s_waitcnt vmcnt(4)" ::: "memory");
            else        asm volatile("s_waitcnt vmcnt(0)" ::: "memory");
            __builtin_amdgcn_s_barrier();
        }
    }
    float inv = (lrun > 0.0f) ? (1.0f / lrun) : 0.0f;
    #pragma unroll
    for (int dsub = 0; dsub < 2; ++dsub) {
        float4 o;
        o.x = oacc[dsub][0] * inv; o.y = oacc[dsub][1] * inv;
        o.z = oacc[dsub][2] * inv; o.w = oacc[dsub][3] * inv;
        *(float4*)(ao + ((size_t)(b * N + i0 + w * 16 + c16)) * H +
                   head * HD + dsub * 16 + g * 4) = o;
    }
}

// ---- split fp32 32-row tile -> bf16 hi/lo LDS (stride 130) ----
__device__ __forceinline__ void stage_split32(
    const float* __restrict__ src, unsigned short* hi, unsigned short* lo, int t) {
    #pragma unroll
    for (int it = 0; it < 4; ++it) {
        int idx4 = it * 256 + t;
        int row = idx4 >> 5, c4 = (idx4 & 31) * 4;
        float4 f = ((const float4*)src)[idx4];
        unsigned short h0 = f2bf(f.x), h1 = f2bf(f.y), h2 = f2bf(f.z), h3 = f2bf(f.w);
        unsigned short l0 = f2bf(f.x - bf2f(h0)), l1 = f2bf(f.y - bf2f(h1));
        unsigned short l2 = f2bf(f.z - bf2f(h2)), l3 = f2bf(f.w - bf2f(h3));
        *(unsigned*)(hi + row * 130 + c4)     = (unsigned)h0 | ((unsigned)h1 << 16);
        *(unsigned*)(hi + row * 130 + c4 + 2) = (unsigned)h2 | ((unsigned)h3 << 16);
        *(unsigned*)(lo + row * 130 + c4)     = (unsigned)l0 | ((unsigned)l1 << 16);
        *(unsigned*)(lo + row * 130 + c4 + 2) = (unsigned)l2 | ((unsigned)l3 << 16);
    }
}

// ---- 3-term split GEMM, 4 col-subtiles at offset bcol0 ----
__device__ __forceinline__ void split_gemm4(
    const unsigned short* ah, const unsigned short* al,
    const unsigned short* wh, const unsigned short* wl,
    int arow, int g, int c16, int bcol0, f32x4* acc) {
    bf16x8 ahf[4], alf[4];
    #pragma unroll
    for (int ks = 0; ks < 4; ++ks) {
        ahf[ks] = *(const bf16x8*)(ah + arow * 130 + ks * 32 + g * 8);
        alf[ks] = *(const bf16x8*)(al + arow * 130 + ks * 32 + g * 8);
    }
    #pragma unroll
    for (int sub = 0; sub < 4; ++sub) {
        int bcol = bcol0 + sub * 16 + c16;
        f32x4 z = {0.f, 0.f, 0.f, 0.f};
        #pragma unroll
        for (int ks = 0; ks < 4; ++ks) {
            bf16x8 bh = *(const bf16x8*)(wh + bcol * 128 + (((ks * 4 + g) ^ (bcol & 7)) * 8));
            bf16x8 bl = *(const bf16x8*)(wl + bcol * 128 + (((ks * 4 + g) ^ (bcol & 7)) * 8));
            z = __builtin_amdgcn_mfma_f32_16x16x32_bf16(ahf[ks], bh, z, 0, 0, 0);
            z = __builtin_amdgcn_mfma_f32_16x16x32_bf16(alf[ks], bh, z, 0, 0, 0);
            z = __builtin_amdgcn_mfma_f32_16x16x32_bf16(ahf[ks], bl, z, 0, 0, 0);
        }
        acc[sub] = z;
    }
}

__device__ __forceinline__ void stage_w(const unsigned short* __restrict__ src,
                                        unsigned short* dst, int t, int w) {
    #pragma unroll
    for (int i = 0; i < 8; ++i) {
        int ci = i * 256 + t, row = ci >> 4, cr = ci & 15;
        gload_lds16(src + (size_t)row * 128 + (cr ^ (row & 7)) * 8,
                    (char*)dst + (i * 4 + w) * 1024);
    }
}

// ------- layer-0: O-proj + LN + relu + residual, 32-row blocks (grid 256) -------
__global__ __launch_bounds__(256) void oln_kernel(
    const float* __restrict__ ao, const unsigned short* __restrict__ woh_l,
    const unsigned short* __restrict__ wol_l, const float* __restrict__ ob,
    const float* __restrict__ lng, const float* __restrict__ lnb,
    float* __restrict__ h, unsigned short* __restrict__ h_bf) {
    __shared__ unsigned short ah[32 * 130], al[32 * 130];
    __shared__ unsigned short wh[128 * 128], wl[128 * 128];
    __shared__ float red1[2][32], red2[2][32];
    const int t = threadIdx.x;
    const int r0 = blockIdx.x * 32;
    const int w = t >> 6, lane = t & 63, g = lane >> 4, c16 = lane & 15;
    const int rw = w & 1, chw = w >> 1;

    stage_w(woh_l, wh, t, w);
    stage_w(wol_l, wl, t, w);
    stage_split32(ao + (size_t)r0 * H, ah, al, t);
    __syncthreads();

    const int arow = rw * 16 + c16;
    f32x4 acc[4];
    split_gemm4(ah, al, wh, wl, arow, g, c16, chw * 64, acc);

    float val[4][4], s1[4] = {0, 0, 0, 0}, s2[4] = {0, 0, 0, 0};
    #pragma unroll
    for (int sub = 0; sub < 4; ++sub) {
        int col = chw * 64 + sub * 16 + c16;
        float bias = ob[col];
        #pragma unroll
        for (int rr = 0; rr < 4; ++rr) {
            float vv = acc[sub][rr] + bias;
            val[sub][rr] = vv;
            s1[rr] += vv;
            s2[rr] += vv * vv;
        }
    }
    #pragma unroll
    for (int rr = 0; rr < 4; ++rr) {
        #pragma unroll
        for (int off = 1; off < 16; off <<= 1) {
            s1[rr] += __shfl_xor(s1[rr], off);
            s2[rr] += __shfl_xor(s2[rr], off);
        }
    }
    if (c16 == 0) {
        #pragma unroll
        for (int rr = 0; rr < 4; ++rr) {
            red1[chw][rw * 16 + g * 4 + rr] = s1[rr];
            red2[chw][rw * 16 + g * 4 + rr] = s2[rr];
        }
    }
    __syncthreads();
    #pragma unroll
    for (int rr = 0; rr < 4; ++rr) {
        int rl = rw * 16 + g * 4 + rr;
        float t1 = red1[0][rl] + red1[1][rl];
        float t2 = red2[0][rl] + red2[1][rl];
        float mu = t1 * (1.0f / H);
        float var = t2 * (1.0f / H) - mu * mu;
        float rsn = rsqrtf(var + EPS);
        int row = r0 + rl;
        #pragma unroll
        for (int sub = 0; sub < 4; ++sub) {
            int col = chw * 64 + sub * 16 + c16;
            float y = (val[sub][rr] - mu) * rsn * lng[col] + lnb[col];
            float hn = fmaxf(y, 0.0f) + h[(size_t)row * H + col];
            h[(size_t)row * H + col] = hn;
            h_bf[(size_t)row * H + col] = f2bf(hn);
        }
    }
}

// ------- layer-1 fused: O-proj + LN + relu + residual + final proj, 32-row blocks -------
__global__ __launch_bounds__(256) void olnfinal_kernel(
    const float* __restrict__ ao, const unsigned short* __restrict__ woh_l,
    const unsigned short* __restrict__ wol_l, const float* __restrict__ ob,
    const float* __restrict__ lng, const float* __restrict__ lnb,
    const float* __restrict__ h, const unsigned short* __restrict__ wfh,
    const unsigned short* __restrict__ wfl, const float* __restrict__ fb,
    float* __restrict__ out) {
    __shared__ unsigned short ah[32 * 130], al[32 * 130];
    __shared__ unsigned short wh[128 * 128], wl[128 * 128];
    __shared__ float red1[2][32], red2[2][32];
    const int t = threadIdx.x;
    const int r0 = blockIdx.x * 32;
    const int w = t >> 6, lane = t & 63, g = lane >> 4, c16 = lane & 15;
    const int rw = w & 1, chw = w >> 1;

    stage_w(woh_l, wh, t, w);
    stage_w(wol_l, wl, t, w);
    stage_split32(ao + (size_t)r0 * H, ah, al, t);
    __syncthreads();

    const int arow = rw * 16 + c16;
    f32x4 acc[4];
    split_gemm4(ah, al, wh, wl, arow, g, c16, chw * 64, acc);

    float val[4][4], s1[4] = {0, 0, 0, 0}, s2[4] = {0, 0, 0, 0};
    #pragma unroll
    for (int sub = 0; sub < 4; ++sub) {
        int col = chw * 64 + sub * 16 + c16;
        float bias = ob[col];
        #pragma unroll
        for (int rr = 0; rr < 4; ++rr) {
            float vv = acc[sub][rr] + bias;
            val[sub][rr] = vv;
            s1[rr] += vv;
            s2[rr] += vv * vv;
        }
    }
    #pragma unroll
    for (int rr = 0; rr < 4; ++rr) {
        #pragma unroll
        for (int off = 1; off < 16; off <<= 1) {
            s1[rr] += __shfl_xor(s1[rr], off);
            s2[rr] += __shfl_xor(s2[rr], off);
        }
    }
    if (c16 == 0) {
        #pragma unroll
        for (int rr = 0; rr < 4; ++rr) {
            red1[chw][rw * 16 + g * 4 + rr] = s1[rr];
            red2[chw][rw * 16 + g * 4 + rr] = s2[rr];
        }
    }
    __syncthreads();   // red ready; all ah/al/wh/wl reads complete
    #pragma unroll
    for (int rr = 0; rr < 4; ++rr) {
        int rl = rw * 16 + g * 4 + rr;
        float t1 = red1[0][rl] + red1[1][rl];
        float t2 = red2[0][rl] + red2[1][rl];
        float mu = t1 * (1.0f / H);
        float var = t2 * (1.0f / H) - mu * mu;
        float rsn = rsqrtf(var + EPS);
        #pragma unroll
        for (int sub = 0; sub < 4; ++sub) {
            int col = chw * 64 + sub * 16 + c16;
            float y = (val[sub][rr] - mu) * rsn * lng[col] + lnb[col];
            float hn = fmaxf(y, 0.0f) + h[(size_t)(r0 + rl) * H + col];
            unsigned short hi = f2bf(hn);
            ah[rl * 130 + col] = hi;
            al[rl * 130 + col] = f2bf(hn - bf2f(hi));
        }
    }
    stage_w(wfh, wh, t, w);
    stage_w(wfl, wl, t, w);
    __syncthreads();

    f32x4 fac[4];
    split_gemm4(ah, al, wh, wl, arow, g, c16, chw * 64, fac);
    #pragma unroll
    for (int sub = 0; sub < 4; ++sub) {
        int col = chw * 64 + sub * 16 + c16;
        float bias = fb[col];
        #pragma unroll
        for (int rr = 0; rr < 4; ++rr) {
            int row = r0 + rw * 16 + g * 4 + rr;
            out[(size_t)row * H + col] = fac[sub][rr] + bias;
        }
    }
}

extern "C" void kernel_launch(void* const* d_in, const int* in_sizes, int n_in,
                              void* d_out, int out_size, void* d_ws, size_t ws_size,
                              hipStream_t stream) {
    const float* x     = (const float*)d_in[0];
    const float* adj   = (const float*)d_in[1];
    const float* enc_w = (const float*)d_in[2];
    const float* enc_b = (const float*)d_in[3];
    const float* q_w   = (const float*)d_in[4];
    const float* q_b   = (const float*)d_in[5];
    const float* k_w   = (const float*)d_in[6];
    const float* k_b   = (const float*)d_in[7];
    const float* v_w   = (const float*)d_in[8];
    const float* v_b   = (const float*)d_in[9];
    const float* o_w   = (const float*)d_in[10];
    const float* o_b   = (const float*)d_in[11];
    const float* ln_g  = (const float*)d_in[12];
    const float* ln_b  = (const float*)d_in[13];
    const float* out_w = (const float*)d_in[14];
    const float* out_b = (const float*)d_in[15];

    const size_t BNH = (size_t)B * N * H;
    float* h  = (float*)d_ws;
    float* ao = h + BNH;
    unsigned short* h_bf = (unsigned short*)(ao + BNH);
    unsigned short* qb = h_bf + BNH;
    unsigned short* kb = qb + BNH;
    unsigned short* vT = kb + BNH;
    unsigned* mbits = (unsigned*)(vT + BNH);
    unsigned short* wqkv = (unsigned short*)(mbits + (size_t)B * N * N / 32);
    float* bqkv = (float*)(wqkv + (size_t)L * 3 * H * H);
    unsigned short* woh = (unsigned short*)(bqkv + L * 3 * H);
    unsigned short* wol = woh + (size_t)L * H * H;
    unsigned short* wfh = wol + (size_t)L * H * H;
    unsigned short* wfl = wfh + (size_t)H * H;

    front_kernel<<<NPACK + NPREP + NENC, 256, 0, stream>>>(
        adj, x, enc_w, enc_b, q_w, k_w, v_w, q_b, k_b, v_b, o_w, out_w,
        mbits, wqkv, bqkv, woh, wol, wfh, wfl, h, h_bf);

    // layer 0
    qkv_kernel<<<B * N / 32, 256, 0, stream>>>(h_bf, wqkv, bqkv, qb, kb, vT);
    attn_kernel<<<B * HEADS * (N / 64), 256, 0, stream>>>(qb, kb, vT, mbits, ao);
    oln_kernel<<<B * N / 32, 256, 0, stream>>>(
        ao, woh, wol, o_b, ln_g, ln_b, h, h_bf);
    // layer 1 (+ final fused)
    qkv_kernel<<<B * N / 32, 256, 0, stream>>>(
        h_bf, wqkv + (size_t)3 * H * H, bqkv + 3 * H, qb, kb, vT);
    attn_kernel<<<B * HEADS * (N / 64), 256, 0, stream>>>(qb, kb, vT, mbits, ao);
    olnfinal_kernel<<<B * N / 32, 256, 0, stream>>>(
        ao, woh + (size_t)H * H, wol + (size_t)H * H, o_b + H,
        ln_g + H, ln_b + H, h, wfh, wfl, out_b, (float*)d_out);
}